// Round 1
// baseline (537.060 us; speedup 1.0000x reference)
//
#include <hip/hip_runtime.h>
#include <math.h>

#define BB 16
#define CC 256
#define NN 1024
#define DQK_ 64
#define DV_ 256
#define NR 192          // 3 * 64 (padded 63-entry tables)
#define EPS_F 1e-5f

// workspace offsets (in floats)
#define OFF_Q   ((size_t)0)          // B*N*64      = 1048576
#define OFF_K   ((size_t)1048576)    // B*N*64      = 1048576
#define OFF_QL  ((size_t)2097152)    // B*N*192     = 3145728
#define OFF_V   ((size_t)5242880)    // B*256*N     = 4194304
#define OFF_ATT ((size_t)9437184)    // B*N*N       = 16777216
#define OFF_BNS ((size_t)26214400)   // 256
#define OFF_BNQ ((size_t)26214656)   // 256
#define OFF_XR  ((size_t)0)          // reuse Q/K/QL region (dead after k_attn)
#define OFF_T   ((size_t)9437184)    // reuse ATT region (dead after k_pv)
// total: 26214912 floats = 104.9 MB

// ---------------------------------------------------------------------------
// K1: Q[b][n][64], K[b][n][64] projections.  64n x 64d tile, K-loop over C.
__global__ __launch_bounds__(256) void k_proj_qk(
    const float* __restrict__ x, const float* __restrict__ qw,
    const float* __restrict__ kw, float* __restrict__ Q, float* __restrict__ Ko)
{
    __shared__ float Xs[64][68];   // [c][n]
    __shared__ float Wq[64][68];   // [c][d]
    __shared__ float Wk[64][68];   // [c][d]
    const int b = blockIdx.y;
    const int n0 = blockIdx.x * 64;
    const int tid = threadIdx.x;
    const int tn = (tid & 15) * 4;
    const int td = (tid >> 4) * 4;
    float aq[4][4] = {}, ak[4][4] = {};
    for (int c0 = 0; c0 < CC; c0 += 64) {
        #pragma unroll
        for (int it = 0; it < 4; ++it) {
            const int i4 = it * 256 + tid;
            const int r  = i4 >> 4;
            const int c4 = (i4 & 15) * 4;
            *(float4*)&Xs[r][c4] =
                *(const float4*)(x + ((size_t)b * CC + c0 + r) * NN + n0 + c4);
            const float4 wq4 = *(const float4*)(qw + (size_t)r * CC + c0 + c4);
            Wq[c4 + 0][r] = wq4.x; Wq[c4 + 1][r] = wq4.y;
            Wq[c4 + 2][r] = wq4.z; Wq[c4 + 3][r] = wq4.w;
            const float4 wk4 = *(const float4*)(kw + (size_t)r * CC + c0 + c4);
            Wk[c4 + 0][r] = wk4.x; Wk[c4 + 1][r] = wk4.y;
            Wk[c4 + 2][r] = wk4.z; Wk[c4 + 3][r] = wk4.w;
        }
        __syncthreads();
        for (int cc = 0; cc < 64; ++cc) {
            float4 xv = *(float4*)&Xs[cc][tn];
            float4 wqv = *(float4*)&Wq[cc][td];
            float4 wkv = *(float4*)&Wk[cc][td];
            const float* xp = (const float*)&xv;
            const float* qp = (const float*)&wqv;
            const float* kp = (const float*)&wkv;
            #pragma unroll
            for (int i = 0; i < 4; ++i)
                #pragma unroll
                for (int j = 0; j < 4; ++j) {
                    aq[i][j] += xp[i] * qp[j];
                    ak[i][j] += xp[i] * kp[j];
                }
        }
        __syncthreads();
    }
    #pragma unroll
    for (int i = 0; i < 4; ++i) {
        float4 oq, ok;
        oq.x = aq[i][0]; oq.y = aq[i][1]; oq.z = aq[i][2]; oq.w = aq[i][3];
        ok.x = ak[i][0]; ok.y = ak[i][1]; ok.z = ak[i][2]; ok.w = ak[i][3];
        *(float4*)(Q  + ((size_t)b * NN + n0 + tn + i) * DQK_ + td) = oq;
        *(float4*)(Ko + ((size_t)b * NN + n0 + tn + i) * DQK_ + td) = ok;
    }
}

// ---------------------------------------------------------------------------
// K1b: QL[b][n][a*64+q] = sum_d Q[b][n][d] * lt_a[q][d]   (q<63; slot 63 = 0)
__global__ __launch_bounds__(256) void k_ql(
    const float* __restrict__ Q, const float* __restrict__ xlt,
    const float* __restrict__ ylt, const float* __restrict__ zlt,
    float* __restrict__ QL)
{
    __shared__ float QsT[64][68];    // [d][n]
    __shared__ float LTt[64][196];   // [d][a*64+q]
    const int b = blockIdx.y;
    const int n0 = blockIdx.x * 64;
    const int tid = threadIdx.x;
    #pragma unroll
    for (int it = 0; it < 4; ++it) {
        const int i4 = it * 256 + tid;
        const int r  = i4 >> 4;
        const int d4 = (i4 & 15) * 4;
        const float4 q4 = *(const float4*)(Q + ((size_t)b * NN + n0 + r) * DQK_ + d4);
        QsT[d4 + 0][r] = q4.x; QsT[d4 + 1][r] = q4.y;
        QsT[d4 + 2][r] = q4.z; QsT[d4 + 3][r] = q4.w;
    }
    for (int o = tid; o < 12288; o += 256) {
        const int a = o >> 12, rem = o & 4095, q = rem >> 6, d = rem & 63;
        const float* lt = (a == 0) ? xlt : ((a == 1) ? ylt : zlt);
        LTt[d][a * 64 + q] = (q < 63) ? lt[q * 64 + d] : 0.0f;
    }
    __syncthreads();
    const int tn2 = (tid & 15) * 4;
    const int ta  = (tid >> 4) * 12;
    float acc[4][12] = {};
    for (int d = 0; d < 64; ++d) {
        float4 qv = *(float4*)&QsT[d][tn2];
        const float* qp = (const float*)&qv;
        #pragma unroll
        for (int j3 = 0; j3 < 3; ++j3) {
            float4 lv = *(float4*)&LTt[d][ta + j3 * 4];
            const float* lp = (const float*)&lv;
            #pragma unroll
            for (int i = 0; i < 4; ++i)
                #pragma unroll
                for (int jj = 0; jj < 4; ++jj)
                    acc[i][j3 * 4 + jj] += qp[i] * lp[jj];
        }
    }
    #pragma unroll
    for (int i = 0; i < 4; ++i)
        #pragma unroll
        for (int j3 = 0; j3 < 3; ++j3) {
            float4 o4;
            o4.x = acc[i][j3 * 4 + 0]; o4.y = acc[i][j3 * 4 + 1];
            o4.z = acc[i][j3 * 4 + 2]; o4.w = acc[i][j3 * 4 + 3];
            *(float4*)(QL + ((size_t)b * NN + n0 + tn2 + i) * NR + ta + j3 * 4) = o4;
        }
}

// ---------------------------------------------------------------------------
// K2: V[b][d][n] = v_w @ x + v_b.  64d x 64n tile.
__global__ __launch_bounds__(256) void k_proj_v(
    const float* __restrict__ x, const float* __restrict__ vw,
    const float* __restrict__ vb, float* __restrict__ V)
{
    __shared__ float Xs[64][68];   // [c][n]
    __shared__ float Ws[64][68];   // [c][d]
    const int b = blockIdx.z;
    const int d0 = blockIdx.y * 64;
    const int n0 = blockIdx.x * 64;
    const int tid = threadIdx.x;
    const int tn = (tid & 15) * 4;
    const int td = (tid >> 4) * 4;
    float acc[4][4] = {};   // [di][ni]
    for (int c0 = 0; c0 < CC; c0 += 64) {
        #pragma unroll
        for (int it = 0; it < 4; ++it) {
            const int i4 = it * 256 + tid;
            const int r  = i4 >> 4;
            const int c4 = (i4 & 15) * 4;
            *(float4*)&Xs[r][c4] =
                *(const float4*)(x + ((size_t)b * CC + c0 + r) * NN + n0 + c4);
            const float4 w4 = *(const float4*)(vw + (size_t)(d0 + r) * CC + c0 + c4);
            Ws[c4 + 0][r] = w4.x; Ws[c4 + 1][r] = w4.y;
            Ws[c4 + 2][r] = w4.z; Ws[c4 + 3][r] = w4.w;
        }
        __syncthreads();
        for (int cc = 0; cc < 64; ++cc) {
            float4 xv = *(float4*)&Xs[cc][tn];
            float4 wv = *(float4*)&Ws[cc][td];
            const float* xp = (const float*)&xv;
            const float* wp = (const float*)&wv;
            #pragma unroll
            for (int di = 0; di < 4; ++di)
                #pragma unroll
                for (int ni = 0; ni < 4; ++ni)
                    acc[di][ni] += wp[di] * xp[ni];
        }
        __syncthreads();
    }
    #pragma unroll
    for (int di = 0; di < 4; ++di) {
        const float bias = vb[d0 + td + di];
        float4 o4;
        o4.x = acc[di][0] + bias; o4.y = acc[di][1] + bias;
        o4.z = acc[di][2] + bias; o4.w = acc[di][3] + bias;
        *(float4*)(V + ((size_t)b * DV_ + d0 + td + di) * NN + n0 + tn) = o4;
    }
}

// ---------------------------------------------------------------------------
// K3: energy + relative-bin terms + softmax -> ATT[b][n][m].  8 rows / block.
__global__ __launch_bounds__(256) void k_attn(
    const float* __restrict__ Q, const float* __restrict__ Kg,
    const float* __restrict__ QL, const int* __restrict__ disc,
    float* __restrict__ ATT)
{
    __shared__ float Qs[8][64];
    __shared__ float QLs[8][192];
    __shared__ int   dnl[8][3];
    __shared__ float Es[8][1024];
    __shared__ float Ks[128][68];
    __shared__ int   dml[128][3];
    const int b = blockIdx.y;
    const int n0 = blockIdx.x * 8;
    const int tid = threadIdx.x;
    if (tid < 128) {
        const int r = tid >> 4, d4 = (tid & 15) * 4;
        *(float4*)&Qs[r][d4] =
            *(const float4*)(Q + ((size_t)b * NN + n0 + r) * DQK_ + d4);
    }
    for (int o = tid; o < 384; o += 256) {           // 8*192/4 float4
        const int r = o / 48, c4 = (o % 48) * 4;
        *(float4*)&QLs[r][c4] =
            *(const float4*)(QL + ((size_t)b * NN + n0 + r) * NR + c4);
    }
    if (tid < 24) {
        const int r = tid / 3, a = tid % 3;
        dnl[r][a] = disc[((size_t)b * NN + n0 + r) * 3 + a];
    }
    for (int mt = 0; mt < 8; ++mt) {
        const int m0 = mt * 128;
        #pragma unroll
        for (int it = 0; it < 8; ++it) {
            const int i4 = it * 256 + tid;
            const int ml = i4 >> 4, d4 = (i4 & 15) * 4;
            *(float4*)&Ks[ml][d4] =
                *(const float4*)(Kg + ((size_t)b * NN + m0 + ml) * DQK_ + d4);
        }
        for (int o = tid; o < 384; o += 256) {
            const int ml = o / 3, a = o % 3;
            dml[ml][a] = disc[((size_t)b * NN + m0 + ml) * 3 + a];
        }
        __syncthreads();
        #pragma unroll
        for (int kx = 0; kx < 4; ++kx) {
            const int o = kx * 256 + tid;
            const int r = o >> 7, ml = o & 127;
            float s = 0.0f;
            #pragma unroll
            for (int d4 = 0; d4 < 64; d4 += 4) {
                float4 qv = *(float4*)&Qs[r][d4];
                float4 kv = *(float4*)&Ks[ml][d4];
                s += qv.x * kv.x + qv.y * kv.y + qv.z * kv.z + qv.w * kv.w;
            }
            #pragma unroll
            for (int a = 0; a < 3; ++a) {
                const int idx = dml[ml][a] - dnl[r][a] + 31;
                s += QLs[r][a * 64 + idx];
            }
            Es[r][m0 + ml] = s * 0.03125f;   // / sqrt(1024)
        }
        __syncthreads();
    }
    // softmax per row (32 lanes / row)
    const int r = tid >> 5, l = tid & 31;
    float mx = -1e30f;
    for (int m = l; m < NN; m += 32) mx = fmaxf(mx, Es[r][m]);
    #pragma unroll
    for (int sh = 16; sh >= 1; sh >>= 1) mx = fmaxf(mx, __shfl_xor(mx, sh));
    float sum = 0.0f;
    for (int m = l; m < NN; m += 32) {
        const float e = __expf(Es[r][m] - mx);
        Es[r][m] = e;
        sum += e;
    }
    #pragma unroll
    for (int sh = 16; sh >= 1; sh >>= 1) sum += __shfl_xor(sum, sh);
    const float inv = 1.0f / sum;
    float* arow = ATT + ((size_t)b * NN + n0 + r) * NN;
    for (int m = l; m < NN; m += 32) arow[m] = Es[r][m] * inv;
}

// ---------------------------------------------------------------------------
// K4: XR[b][d][m] = sum_n V[b][d][n] * ATT[b][n][m].  64d x 64m tile, K=1024.
__global__ __launch_bounds__(256) void k_pv(
    const float* __restrict__ V, const float* __restrict__ ATT,
    float* __restrict__ XR)
{
    __shared__ float As[32][68];   // [k][d]
    __shared__ float Bs[32][68];   // [k][m]
    const int b = blockIdx.z;
    const int d0 = blockIdx.y * 64;
    const int m0 = blockIdx.x * 64;
    const int tid = threadIdx.x;
    const int tm = (tid & 15) * 4;
    const int td = (tid >> 4) * 4;
    float acc[4][4] = {};   // [di][mi]
    for (int nk = 0; nk < NN; nk += 32) {
        {
            const int dd = tid >> 2, g = tid & 3;
            const float* src = V + ((size_t)b * DV_ + d0 + dd) * NN + nk + g * 8;
            const float4 v1 = *(const float4*)(src);
            const float4 v2 = *(const float4*)(src + 4);
            As[g * 8 + 0][dd] = v1.x; As[g * 8 + 1][dd] = v1.y;
            As[g * 8 + 2][dd] = v1.z; As[g * 8 + 3][dd] = v1.w;
            As[g * 8 + 4][dd] = v2.x; As[g * 8 + 5][dd] = v2.y;
            As[g * 8 + 6][dd] = v2.z; As[g * 8 + 7][dd] = v2.w;
        }
        #pragma unroll
        for (int it = 0; it < 2; ++it) {
            const int i4 = it * 256 + tid;
            const int kk = i4 >> 4, m4 = (i4 & 15) * 4;
            *(float4*)&Bs[kk][m4] =
                *(const float4*)(ATT + ((size_t)b * NN + nk + kk) * NN + m0 + m4);
        }
        __syncthreads();
        #pragma unroll
        for (int kk = 0; kk < 32; ++kk) {
            float4 a4 = *(float4*)&As[kk][td];
            float4 b4 = *(float4*)&Bs[kk][tm];
            const float* ap = (const float*)&a4;
            const float* bp = (const float*)&b4;
            #pragma unroll
            for (int di = 0; di < 4; ++di)
                #pragma unroll
                for (int mi = 0; mi < 4; ++mi)
                    acc[di][mi] += ap[di] * bp[mi];
        }
        __syncthreads();
    }
    #pragma unroll
    for (int di = 0; di < 4; ++di) {
        float4 o4;
        o4.x = acc[di][0]; o4.y = acc[di][1]; o4.z = acc[di][2]; o4.w = acc[di][3];
        *(float4*)(XR + ((size_t)b * DV_ + d0 + td + di) * NN + m0 + tm) = o4;
    }
}

// ---------------------------------------------------------------------------
// K5: T[b][c][n] = trans_w @ (x - XR) + trans_b ; accumulate BN sums per c.
__global__ __launch_bounds__(256) void k_trans(
    const float* __restrict__ x, const float* __restrict__ XR,
    const float* __restrict__ tw, const float* __restrict__ tb,
    float* __restrict__ T, float* __restrict__ bnS, float* __restrict__ bnQ)
{
    __shared__ float Hs[64][68];   // [d][n]
    __shared__ float Ws[64][68];   // [d][c]
    __shared__ float sS[64], sQ[64];
    const int b = blockIdx.z;
    const int c0 = blockIdx.y * 64;
    const int n0 = blockIdx.x * 64;
    const int tid = threadIdx.x;
    const int tn = (tid & 15) * 4;
    const int tc = (tid >> 4) * 4;
    if (tid < 64) { sS[tid] = 0.0f; sQ[tid] = 0.0f; }
    float acc[4][4] = {};   // [ci][ni]
    for (int d0 = 0; d0 < DV_; d0 += 64) {
        #pragma unroll
        for (int it = 0; it < 4; ++it) {
            const int i4 = it * 256 + tid;
            const int r  = i4 >> 4;
            const int c4 = (i4 & 15) * 4;
            const size_t off = ((size_t)b * CC + d0 + r) * NN + n0 + c4;
            const float4 xv = *(const float4*)(x + off);
            const float4 rv = *(const float4*)(XR + off);
            float4 h;
            h.x = xv.x - rv.x; h.y = xv.y - rv.y;
            h.z = xv.z - rv.z; h.w = xv.w - rv.w;
            *(float4*)&Hs[r][c4] = h;
            const float4 w4 = *(const float4*)(tw + (size_t)(c0 + r) * DV_ + d0 + c4);
            Ws[c4 + 0][r] = w4.x; Ws[c4 + 1][r] = w4.y;
            Ws[c4 + 2][r] = w4.z; Ws[c4 + 3][r] = w4.w;
        }
        __syncthreads();
        for (int dd = 0; dd < 64; ++dd) {
            float4 hv = *(float4*)&Hs[dd][tn];
            float4 wv = *(float4*)&Ws[dd][tc];
            const float* hp = (const float*)&hv;
            const float* wp = (const float*)&wv;
            #pragma unroll
            for (int ci = 0; ci < 4; ++ci)
                #pragma unroll
                for (int ni = 0; ni < 4; ++ni)
                    acc[ci][ni] += wp[ci] * hp[ni];
        }
        __syncthreads();
    }
    #pragma unroll
    for (int ci = 0; ci < 4; ++ci) {
        const float bias = tb[c0 + tc + ci];
        float s = 0.0f, q = 0.0f;
        float4 o4;
        float* op = (float*)&o4;
        #pragma unroll
        for (int ni = 0; ni < 4; ++ni) {
            const float v = acc[ci][ni] + bias;
            op[ni] = v;
            s += v;
            q += v * v;
        }
        *(float4*)(T + ((size_t)b * CC + c0 + tc + ci) * NN + n0 + tn) = o4;
        atomicAdd(&sS[tc + ci], s);
        atomicAdd(&sQ[tc + ci], q);
    }
    __syncthreads();
    if (tid < 64) {
        atomicAdd(&bnS[c0 + tid], sS[tid]);
        atomicAdd(&bnQ[c0 + tid], sQ[tid]);
    }
}

// ---------------------------------------------------------------------------
// K6: out = x + relu(bn(T))
__global__ __launch_bounds__(256) void k_out(
    const float* __restrict__ x, const float* __restrict__ T,
    const float* __restrict__ gamma, const float* __restrict__ beta,
    const float* __restrict__ bnS, const float* __restrict__ bnQ,
    float* __restrict__ out)
{
    const int i4 = blockIdx.x * 256 + threadIdx.x;  // float4 idx; one (b,c) row / block
    const int c = (i4 >> 8) & 255;
    const float meanv = bnS[c] * (1.0f / 16384.0f);
    const float varv  = bnQ[c] * (1.0f / 16384.0f) - meanv * meanv;
    const float inv   = rsqrtf(varv + EPS_F);
    const float g = gamma[c] * inv;
    const float be = beta[c];
    const float4 t4 = *(const float4*)(T + (size_t)i4 * 4);
    const float4 x4 = *(const float4*)(x + (size_t)i4 * 4);
    float4 o;
    o.x = x4.x + fmaxf(g * (t4.x - meanv) + be, 0.0f);
    o.y = x4.y + fmaxf(g * (t4.y - meanv) + be, 0.0f);
    o.z = x4.z + fmaxf(g * (t4.z - meanv) + be, 0.0f);
    o.w = x4.w + fmaxf(g * (t4.w - meanv) + be, 0.0f);
    *(float4*)(out + (size_t)i4 * 4) = o;
}

// ---------------------------------------------------------------------------
extern "C" void kernel_launch(void* const* d_in, const int* in_sizes, int n_in,
                              void* d_out, int out_size, void* d_ws, size_t ws_size,
                              hipStream_t stream)
{
    const float* x     = (const float*)d_in[0];
    const int*   disc  = (const int*)d_in[1];
    // d_in[2] = xyz (unused by reference)
    const float* qw    = (const float*)d_in[3];
    const float* kw    = (const float*)d_in[4];
    const float* vw    = (const float*)d_in[5];
    const float* vb    = (const float*)d_in[6];
    const float* tw    = (const float*)d_in[7];
    const float* tb    = (const float*)d_in[8];
    const float* gamma = (const float*)d_in[9];
    const float* beta  = (const float*)d_in[10];
    const float* xlt   = (const float*)d_in[11];
    const float* ylt   = (const float*)d_in[12];
    const float* zlt   = (const float*)d_in[13];
    float* ws  = (float*)d_ws;
    float* out = (float*)d_out;

    float* Q   = ws + OFF_Q;
    float* Kb  = ws + OFF_K;
    float* QL  = ws + OFF_QL;
    float* V   = ws + OFF_V;
    float* ATT = ws + OFF_ATT;
    float* XR  = ws + OFF_XR;
    float* T   = ws + OFF_T;
    float* bnS = ws + OFF_BNS;
    float* bnQ = ws + OFF_BNQ;

    hipMemsetAsync(bnS, 0, 512 * sizeof(float), stream);

    k_proj_qk<<<dim3(NN / 64, BB), 256, 0, stream>>>(x, qw, kw, Q, Kb);
    k_ql     <<<dim3(NN / 64, BB), 256, 0, stream>>>(Q, xlt, ylt, zlt, QL);
    k_proj_v <<<dim3(NN / 64, DV_ / 64, BB), 256, 0, stream>>>(x, vw, vb, V);
    k_attn   <<<dim3(NN / 8, BB), 256, 0, stream>>>(Q, Kb, QL, disc, ATT);
    k_pv     <<<dim3(NN / 64, DV_ / 64, BB), 256, 0, stream>>>(V, ATT, XR);
    k_trans  <<<dim3(NN / 64, CC / 64, BB), 256, 0, stream>>>(x, XR, tw, tb, T, bnS, bnQ);
    k_out    <<<dim3((BB * CC * NN / 4) / 256), 256, 0, stream>>>(x, T, gamma, beta, bnS, bnQ, out);
}

// Round 2
// 240.576 us; speedup vs baseline: 2.2324x; 2.2324x over previous
//
#include <hip/hip_runtime.h>
#include <math.h>

#define BB 16
#define CC 256
#define NN 1024
#define DQK_ 64
#define DV_ 256
#define NR 192          // 3 * 64 (padded 63-entry tables)
#define EPS_F 1e-5f

// workspace offsets (in float units)
#define OFF_QB  ((size_t)0)          // B*N*64 bf16   = 524288 f
#define OFF_KB  ((size_t)524288)     // B*N*64 bf16   = 524288 f
#define OFF_QL  ((size_t)1048576)    // B*N*192 f32   = 3145728 f
#define OFF_VB  ((size_t)4194304)    // B*256*N bf16  = 2097152 f
#define OFF_ATT ((size_t)6291456)    // B*N*N bf16    = 8388608 f  (transposed: [b][m][n])
#define OFF_XR  ((size_t)0)          // f32, overlays QB/KB/QL (dead after k_attn) = 4194304 f
#define OFF_T   ((size_t)6291456)    // f32, overlays ATT (dead after k_pv) = 4194304 f
#define OFF_BNS ((size_t)14680064)
#define OFF_BNQ ((size_t)14680320)
// total 14680576 floats = 58.7 MB

typedef __attribute__((ext_vector_type(8))) short short8;
typedef __attribute__((ext_vector_type(4))) float f32x4;

__device__ __forceinline__ unsigned short f2b(float f) {
    unsigned int u = __float_as_uint(f);
    u = u + 0x7fffu + ((u >> 16) & 1u);      // round-to-nearest-even
    return (unsigned short)(u >> 16);
}
__device__ __forceinline__ float b2f(unsigned short s) {
    return __uint_as_float(((unsigned int)s) << 16);
}

// ---------------------------------------------------------------------------
// K1: Q,K projections -> bf16 [b][n][64]
__global__ __launch_bounds__(256) void k_proj_qk(
    const float* __restrict__ x, const float* __restrict__ qw,
    const float* __restrict__ kw, unsigned short* __restrict__ Qb,
    unsigned short* __restrict__ Kb)
{
    __shared__ float Xs[64][68];   // [c][n]
    __shared__ float Wq[64][68];   // [c][d]
    __shared__ float Wk[64][68];   // [c][d]
    const int b = blockIdx.y;
    const int n0 = blockIdx.x * 64;
    const int tid = threadIdx.x;
    const int tn = (tid & 15) * 4;
    const int td = (tid >> 4) * 4;
    float aq[4][4] = {}, ak[4][4] = {};
    for (int c0 = 0; c0 < CC; c0 += 64) {
        #pragma unroll
        for (int it = 0; it < 4; ++it) {
            const int i4 = it * 256 + tid;
            const int r  = i4 >> 4;
            const int c4 = (i4 & 15) * 4;
            *(float4*)&Xs[r][c4] =
                *(const float4*)(x + ((size_t)b * CC + c0 + r) * NN + n0 + c4);
            const float4 wq4 = *(const float4*)(qw + (size_t)r * CC + c0 + c4);
            Wq[c4 + 0][r] = wq4.x; Wq[c4 + 1][r] = wq4.y;
            Wq[c4 + 2][r] = wq4.z; Wq[c4 + 3][r] = wq4.w;
            const float4 wk4 = *(const float4*)(kw + (size_t)r * CC + c0 + c4);
            Wk[c4 + 0][r] = wk4.x; Wk[c4 + 1][r] = wk4.y;
            Wk[c4 + 2][r] = wk4.z; Wk[c4 + 3][r] = wk4.w;
        }
        __syncthreads();
        for (int cc = 0; cc < 64; ++cc) {
            float4 xv = *(float4*)&Xs[cc][tn];
            float4 wqv = *(float4*)&Wq[cc][td];
            float4 wkv = *(float4*)&Wk[cc][td];
            const float* xp = (const float*)&xv;
            const float* qp = (const float*)&wqv;
            const float* kp = (const float*)&wkv;
            #pragma unroll
            for (int i = 0; i < 4; ++i)
                #pragma unroll
                for (int j = 0; j < 4; ++j) {
                    aq[i][j] += xp[i] * qp[j];
                    ak[i][j] += xp[i] * kp[j];
                }
        }
        __syncthreads();
    }
    #pragma unroll
    for (int i = 0; i < 4; ++i) {
        ushort4 oq, ok;
        oq.x = f2b(aq[i][0]); oq.y = f2b(aq[i][1]);
        oq.z = f2b(aq[i][2]); oq.w = f2b(aq[i][3]);
        ok.x = f2b(ak[i][0]); ok.y = f2b(ak[i][1]);
        ok.z = f2b(ak[i][2]); ok.w = f2b(ak[i][3]);
        *(ushort4*)(Qb + ((size_t)b * NN + n0 + tn + i) * DQK_ + td) = oq;
        *(ushort4*)(Kb + ((size_t)b * NN + n0 + tn + i) * DQK_ + td) = ok;
    }
}

// ---------------------------------------------------------------------------
// K1b: QL[b][n][a*64+q] = sum_d Q[b][n][d] * lt_a[q][d]  (fp32 out, bf16 Q in)
__global__ __launch_bounds__(256) void k_ql(
    const unsigned short* __restrict__ Qb, const float* __restrict__ xlt,
    const float* __restrict__ ylt, const float* __restrict__ zlt,
    float* __restrict__ QL)
{
    __shared__ float QsT[64][68];    // [d][n]
    __shared__ float LTt[64][196];   // [d][a*64+q]
    const int b = blockIdx.y;
    const int n0 = blockIdx.x * 64;
    const int tid = threadIdx.x;
    #pragma unroll
    for (int it = 0; it < 4; ++it) {
        const int i4 = it * 256 + tid;
        const int r  = i4 >> 4;
        const int d4 = (i4 & 15) * 4;
        const ushort4 q4 = *(const ushort4*)(Qb + ((size_t)b * NN + n0 + r) * DQK_ + d4);
        QsT[d4 + 0][r] = b2f(q4.x); QsT[d4 + 1][r] = b2f(q4.y);
        QsT[d4 + 2][r] = b2f(q4.z); QsT[d4 + 3][r] = b2f(q4.w);
    }
    for (int o = tid; o < 12288; o += 256) {
        const int a = o >> 12, rem = o & 4095, q = rem >> 6, d = rem & 63;
        const float* lt = (a == 0) ? xlt : ((a == 1) ? ylt : zlt);
        LTt[d][a * 64 + q] = (q < 63) ? lt[q * 64 + d] : 0.0f;
    }
    __syncthreads();
    const int tn2 = (tid & 15) * 4;
    const int ta  = (tid >> 4) * 12;
    float acc[4][12] = {};
    for (int d = 0; d < 64; ++d) {
        float4 qv = *(float4*)&QsT[d][tn2];
        const float* qp = (const float*)&qv;
        #pragma unroll
        for (int j3 = 0; j3 < 3; ++j3) {
            float4 lv = *(float4*)&LTt[d][ta + j3 * 4];
            const float* lp = (const float*)&lv;
            #pragma unroll
            for (int i = 0; i < 4; ++i)
                #pragma unroll
                for (int jj = 0; jj < 4; ++jj)
                    acc[i][j3 * 4 + jj] += qp[i] * lp[jj];
        }
    }
    #pragma unroll
    for (int i = 0; i < 4; ++i)
        #pragma unroll
        for (int j3 = 0; j3 < 3; ++j3) {
            float4 o4;
            o4.x = acc[i][j3 * 4 + 0]; o4.y = acc[i][j3 * 4 + 1];
            o4.z = acc[i][j3 * 4 + 2]; o4.w = acc[i][j3 * 4 + 3];
            *(float4*)(QL + ((size_t)b * NN + n0 + tn2 + i) * NR + ta + j3 * 4) = o4;
        }
}

// ---------------------------------------------------------------------------
// K2: V[b][d][n] bf16 = v_w @ x + v_b
__global__ __launch_bounds__(256) void k_proj_v(
    const float* __restrict__ x, const float* __restrict__ vw,
    const float* __restrict__ vb, unsigned short* __restrict__ Vb)
{
    __shared__ float Xs[64][68];   // [c][n]
    __shared__ float Ws[64][68];   // [c][d]
    const int b = blockIdx.z;
    const int d0 = blockIdx.y * 64;
    const int n0 = blockIdx.x * 64;
    const int tid = threadIdx.x;
    const int tn = (tid & 15) * 4;
    const int td = (tid >> 4) * 4;
    float acc[4][4] = {};   // [di][ni]
    for (int c0 = 0; c0 < CC; c0 += 64) {
        #pragma unroll
        for (int it = 0; it < 4; ++it) {
            const int i4 = it * 256 + tid;
            const int r  = i4 >> 4;
            const int c4 = (i4 & 15) * 4;
            *(float4*)&Xs[r][c4] =
                *(const float4*)(x + ((size_t)b * CC + c0 + r) * NN + n0 + c4);
            const float4 w4 = *(const float4*)(vw + (size_t)(d0 + r) * CC + c0 + c4);
            Ws[c4 + 0][r] = w4.x; Ws[c4 + 1][r] = w4.y;
            Ws[c4 + 2][r] = w4.z; Ws[c4 + 3][r] = w4.w;
        }
        __syncthreads();
        for (int cc = 0; cc < 64; ++cc) {
            float4 xv = *(float4*)&Xs[cc][tn];
            float4 wv = *(float4*)&Ws[cc][td];
            const float* xp = (const float*)&xv;
            const float* wp = (const float*)&wv;
            #pragma unroll
            for (int di = 0; di < 4; ++di)
                #pragma unroll
                for (int ni = 0; ni < 4; ++ni)
                    acc[di][ni] += wp[di] * xp[ni];
        }
        __syncthreads();
    }
    #pragma unroll
    for (int di = 0; di < 4; ++di) {
        const float bias = vb[d0 + td + di];
        ushort4 o4;
        o4.x = f2b(acc[di][0] + bias); o4.y = f2b(acc[di][1] + bias);
        o4.z = f2b(acc[di][2] + bias); o4.w = f2b(acc[di][3] + bias);
        *(ushort4*)(Vb + ((size_t)b * DV_ + d0 + td + di) * NN + n0 + tn) = o4;
    }
}

// ---------------------------------------------------------------------------
// K3: energy (MFMA bf16, swapped operands) + rel gathers + softmax.
// Block: 16 q-rows, 4 waves split the 1024 m-columns. Output ATT_T[b][m][n] bf16.
__global__ __launch_bounds__(256) void k_attn(
    const unsigned short* __restrict__ Qb, const unsigned short* __restrict__ Kb,
    const float* __restrict__ QL, const int* __restrict__ disc,
    unsigned short* __restrict__ att)
{
    __shared__ float QLs[16][193];     // stride 193 breaks bank aliasing
    __shared__ int   dmlT[3][1024];
    __shared__ float redM[4][16];
    __shared__ float redS[4][16];
    const int b = blockIdx.y;
    const int q0 = blockIdx.x * 16;
    const int tid = threadIdx.x;
    const int l = tid & 63, w = tid >> 6;
    const int l15 = l & 15, l4 = l >> 4;

    for (int o = tid; o < 16 * NR; o += 256) {
        const int r = o / NR, c = o - r * NR;
        QLs[r][c] = QL[((size_t)b * NN + q0 + r) * NR + c];
    }
    for (int o = tid; o < 3 * NN; o += 256) {
        const int a = o >> 10, m = o & 1023;
        dmlT[a][m] = disc[((size_t)b * NN + m) * 3 + a];
    }
    __syncthreads();

    const int q = q0 + l15;
    const int dn0 = disc[((size_t)b * NN + q) * 3 + 0];
    const int dn1 = disc[((size_t)b * NN + q) * 3 + 1];
    const int dn2 = disc[((size_t)b * NN + q) * 3 + 2];

    const unsigned short* qp = Qb + ((size_t)b * NN + q) * DQK_ + l4 * 8;
    const short8 qf0 = *(const short8*)qp;
    const short8 qf1 = *(const short8*)(qp + 32);

    float s[64];
    #pragma unroll
    for (int t = 0; t < 16; ++t) {
        const int m0 = t * 64 + w * 16;
        const unsigned short* kp = Kb + ((size_t)b * NN + m0 + l15) * DQK_ + l4 * 8;
        const short8 kf0 = *(const short8*)kp;
        const short8 kf1 = *(const short8*)(kp + 32);
        f32x4 acc = {0.f, 0.f, 0.f, 0.f};
        acc = __builtin_amdgcn_mfma_f32_16x16x32_bf16(kf0, qf0, acc, 0, 0, 0);
        acc = __builtin_amdgcn_mfma_f32_16x16x32_bf16(kf1, qf1, acc, 0, 0, 0);
        // D[m][q]: col = lane&15 = q, row = (lane>>4)*4 + r = m offset
        #pragma unroll
        for (int r = 0; r < 4; ++r) {
            const int m = m0 + l4 * 4 + r;
            const int i0 = dmlT[0][m] - dn0 + 31;
            const int i1 = dmlT[1][m] - dn1 + 31;
            const int i2 = dmlT[2][m] - dn2 + 31;
            const float rel = QLs[l15][i0] + QLs[l15][64 + i1] + QLs[l15][128 + i2];
            s[t * 4 + r] = (acc[r] + rel) * 0.03125f;
        }
    }

    // per-q-row softmax over m (64 vals in-lane, x4 lanes, x4 waves)
    float mx = -1e30f;
    #pragma unroll
    for (int i = 0; i < 64; ++i) mx = fmaxf(mx, s[i]);
    mx = fmaxf(mx, __shfl_xor(mx, 16));
    mx = fmaxf(mx, __shfl_xor(mx, 32));
    if (l < 16) redM[w][l] = mx;
    __syncthreads();
    mx = fmaxf(fmaxf(redM[0][l15], redM[1][l15]), fmaxf(redM[2][l15], redM[3][l15]));

    float sum = 0.f;
    #pragma unroll
    for (int i = 0; i < 64; ++i) { s[i] = __expf(s[i] - mx); sum += s[i]; }
    sum += __shfl_xor(sum, 16);
    sum += __shfl_xor(sum, 32);
    if (l < 16) redS[w][l] = sum;
    __syncthreads();
    const float inv = 1.0f /
        (redS[0][l15] + redS[1][l15] + redS[2][l15] + redS[3][l15]);

    #pragma unroll
    for (int t = 0; t < 16; ++t)
        #pragma unroll
        for (int r = 0; r < 4; ++r) {
            const int m = t * 64 + w * 16 + l4 * 4 + r;
            att[((size_t)b * NN + m) * NN + q] = f2b(s[t * 4 + r] * inv);
        }
}

// ---------------------------------------------------------------------------
// K4: XR[b][d][m] = sum_n V[d][n] * ATT_T[m][n]  -- MFMA, both operands
// row-major over contraction dim n. Block tile 64d x 64m, wave quadrant 32x32.
__global__ __launch_bounds__(256) void k_pv(
    const unsigned short* __restrict__ Vb, const unsigned short* __restrict__ att,
    float* __restrict__ XR)
{
    const int b = blockIdx.z;
    const int d0 = blockIdx.y * 64;
    const int m0 = blockIdx.x * 64;
    const int tid = threadIdx.x;
    const int l = tid & 63, w = tid >> 6;
    const int l15 = l & 15, l4 = l >> 4;
    const int wd = (w >> 1) * 32, wm = (w & 1) * 32;
    const unsigned short* a0p = Vb + ((size_t)(b * DV_ + d0 + wd + l15)) * NN + l4 * 8;
    const unsigned short* a1p = a0p + 16 * NN;
    const unsigned short* b0p = att + ((size_t)(b * NN + m0 + wm + l15)) * NN + l4 * 8;
    const unsigned short* b1p = b0p + 16 * NN;
    f32x4 acc00 = {0.f,0.f,0.f,0.f}, acc01 = {0.f,0.f,0.f,0.f};
    f32x4 acc10 = {0.f,0.f,0.f,0.f}, acc11 = {0.f,0.f,0.f,0.f};
    #pragma unroll 4
    for (int nk = 0; nk < NN; nk += 32) {
        const short8 a0 = *(const short8*)(a0p + nk);
        const short8 a1 = *(const short8*)(a1p + nk);
        const short8 b0v = *(const short8*)(b0p + nk);
        const short8 b1v = *(const short8*)(b1p + nk);
        acc00 = __builtin_amdgcn_mfma_f32_16x16x32_bf16(a0, b0v, acc00, 0, 0, 0);
        acc01 = __builtin_amdgcn_mfma_f32_16x16x32_bf16(a0, b1v, acc01, 0, 0, 0);
        acc10 = __builtin_amdgcn_mfma_f32_16x16x32_bf16(a1, b0v, acc10, 0, 0, 0);
        acc11 = __builtin_amdgcn_mfma_f32_16x16x32_bf16(a1, b1v, acc11, 0, 0, 0);
    }
    // D[d][m]: col = lane&15 = m, row = (lane>>4)*4 + r = d
    #pragma unroll
    for (int r = 0; r < 4; ++r) {
        const int dA = d0 + wd + l4 * 4 + r;
        const int mA = m0 + wm + l15;
        XR[((size_t)b * DV_ + dA) * NN + mA]            = acc00[r];
        XR[((size_t)b * DV_ + dA) * NN + mA + 16]       = acc01[r];
        XR[((size_t)b * DV_ + dA + 16) * NN + mA]       = acc10[r];
        XR[((size_t)b * DV_ + dA + 16) * NN + mA + 16]  = acc11[r];
    }
}

// ---------------------------------------------------------------------------
// K5: T[b][c][n] = trans_w @ (x - XR) + trans_b ; accumulate BN sums per c.
__global__ __launch_bounds__(256) void k_trans(
    const float* __restrict__ x, const float* __restrict__ XR,
    const float* __restrict__ tw, const float* __restrict__ tb,
    float* __restrict__ T, float* __restrict__ bnS, float* __restrict__ bnQ)
{
    __shared__ float Hs[64][68];   // [d][n]
    __shared__ float Ws[64][68];   // [d][c]
    __shared__ float sS[64], sQ[64];
    const int b = blockIdx.z;
    const int c0 = blockIdx.y * 64;
    const int n0 = blockIdx.x * 64;
    const int tid = threadIdx.x;
    const int tn = (tid & 15) * 4;
    const int tc = (tid >> 4) * 4;
    if (tid < 64) { sS[tid] = 0.0f; sQ[tid] = 0.0f; }
    float acc[4][4] = {};   // [ci][ni]
    for (int d0 = 0; d0 < DV_; d0 += 64) {
        #pragma unroll
        for (int it = 0; it < 4; ++it) {
            const int i4 = it * 256 + tid;
            const int r  = i4 >> 4;
            const int c4 = (i4 & 15) * 4;
            const size_t off = ((size_t)b * CC + d0 + r) * NN + n0 + c4;
            const float4 xv = *(const float4*)(x + off);
            const float4 rv = *(const float4*)(XR + off);
            float4 h;
            h.x = xv.x - rv.x; h.y = xv.y - rv.y;
            h.z = xv.z - rv.z; h.w = xv.w - rv.w;
            *(float4*)&Hs[r][c4] = h;
            const float4 w4 = *(const float4*)(tw + (size_t)(c0 + r) * DV_ + d0 + c4);
            Ws[c4 + 0][r] = w4.x; Ws[c4 + 1][r] = w4.y;
            Ws[c4 + 2][r] = w4.z; Ws[c4 + 3][r] = w4.w;
        }
        __syncthreads();
        for (int dd = 0; dd < 64; ++dd) {
            float4 hv = *(float4*)&Hs[dd][tn];
            float4 wv = *(float4*)&Ws[dd][tc];
            const float* hp = (const float*)&hv;
            const float* wp = (const float*)&wv;
            #pragma unroll
            for (int ci = 0; ci < 4; ++ci)
                #pragma unroll
                for (int ni = 0; ni < 4; ++ni)
                    acc[ci][ni] += wp[ci] * hp[ni];
        }
        __syncthreads();
    }
    #pragma unroll
    for (int ci = 0; ci < 4; ++ci) {
        const float bias = tb[c0 + tc + ci];
        float s = 0.0f, qq = 0.0f;
        float4 o4;
        float* op = (float*)&o4;
        #pragma unroll
        for (int ni = 0; ni < 4; ++ni) {
            const float v = acc[ci][ni] + bias;
            op[ni] = v;
            s += v;
            qq += v * v;
        }
        *(float4*)(T + ((size_t)b * CC + c0 + tc + ci) * NN + n0 + tn) = o4;
        atomicAdd(&sS[tc + ci], s);
        atomicAdd(&sQ[tc + ci], qq);
    }
    __syncthreads();
    if (tid < 64) {
        atomicAdd(&bnS[c0 + tid], sS[tid]);
        atomicAdd(&bnQ[c0 + tid], sQ[tid]);
    }
}

// ---------------------------------------------------------------------------
// K6: out = x + relu(bn(T))
__global__ __launch_bounds__(256) void k_out(
    const float* __restrict__ x, const float* __restrict__ T,
    const float* __restrict__ gamma, const float* __restrict__ beta,
    const float* __restrict__ bnS, const float* __restrict__ bnQ,
    float* __restrict__ out)
{
    const int i4 = blockIdx.x * 256 + threadIdx.x;
    const int c = (i4 >> 8) & 255;
    const float meanv = bnS[c] * (1.0f / 16384.0f);
    const float varv  = bnQ[c] * (1.0f / 16384.0f) - meanv * meanv;
    const float inv   = rsqrtf(varv + EPS_F);
    const float g = gamma[c] * inv;
    const float be = beta[c];
    const float4 t4 = *(const float4*)(T + (size_t)i4 * 4);
    const float4 x4 = *(const float4*)(x + (size_t)i4 * 4);
    float4 o;
    o.x = x4.x + fmaxf(g * (t4.x - meanv) + be, 0.0f);
    o.y = x4.y + fmaxf(g * (t4.y - meanv) + be, 0.0f);
    o.z = x4.z + fmaxf(g * (t4.z - meanv) + be, 0.0f);
    o.w = x4.w + fmaxf(g * (t4.w - meanv) + be, 0.0f);
    *(float4*)(out + (size_t)i4 * 4) = o;
}

// ---------------------------------------------------------------------------
extern "C" void kernel_launch(void* const* d_in, const int* in_sizes, int n_in,
                              void* d_out, int out_size, void* d_ws, size_t ws_size,
                              hipStream_t stream)
{
    const float* x     = (const float*)d_in[0];
    const int*   disc  = (const int*)d_in[1];
    // d_in[2] = xyz (unused by reference)
    const float* qw    = (const float*)d_in[3];
    const float* kw    = (const float*)d_in[4];
    const float* vw    = (const float*)d_in[5];
    const float* vb    = (const float*)d_in[6];
    const float* tw    = (const float*)d_in[7];
    const float* tb    = (const float*)d_in[8];
    const float* gamma = (const float*)d_in[9];
    const float* beta  = (const float*)d_in[10];
    const float* xlt   = (const float*)d_in[11];
    const float* ylt   = (const float*)d_in[12];
    const float* zlt   = (const float*)d_in[13];
    float* ws  = (float*)d_ws;
    float* out = (float*)d_out;

    unsigned short* Qb  = (unsigned short*)(ws + OFF_QB);
    unsigned short* Kb  = (unsigned short*)(ws + OFF_KB);
    float*          QL  = ws + OFF_QL;
    unsigned short* Vb  = (unsigned short*)(ws + OFF_VB);
    unsigned short* ATT = (unsigned short*)(ws + OFF_ATT);
    float*          XR  = ws + OFF_XR;
    float*          T   = ws + OFF_T;
    float*          bnS = ws + OFF_BNS;
    float*          bnQ = ws + OFF_BNQ;

    hipMemsetAsync(bnS, 0, 512 * sizeof(float), stream);

    k_proj_qk<<<dim3(NN / 64, BB), 256, 0, stream>>>(x, qw, kw, Qb, Kb);
    k_ql     <<<dim3(NN / 64, BB), 256, 0, stream>>>(Qb, xlt, ylt, zlt, QL);
    k_proj_v <<<dim3(NN / 64, DV_ / 64, BB), 256, 0, stream>>>(x, vw, vb, Vb);
    k_attn   <<<dim3(NN / 16, BB), 256, 0, stream>>>(Qb, Kb, QL, disc, ATT);
    k_pv     <<<dim3(NN / 64, DV_ / 64, BB), 256, 0, stream>>>(Vb, ATT, XR);
    k_trans  <<<dim3(NN / 64, CC / 64, BB), 256, 0, stream>>>(x, XR, tw, tb, T, bnS, bnQ);
    k_out    <<<dim3((BB * CC * NN / 4) / 256), 256, 0, stream>>>(x, T, gamma, beta, bnS, bnQ, out);
}

// Round 5
// 185.615 us; speedup vs baseline: 2.8934x; 1.2961x over previous
//
#include <hip/hip_runtime.h>
#include <math.h>

#define BB 16
#define CC 256
#define NN 1024
#define DQK_ 64
#define DV_ 256
#define NR 192          // 3 * 64 (padded 63-entry tables)
#define EPS_F 1e-5f

// workspace offsets (float units)
#define OFF_XT  ((size_t)0)           // bf16 [B][N][C]   = 2097152 f
#define OFF_QB  ((size_t)2097152)     // bf16 [B][N][64]  = 524288 f
#define OFF_KB  ((size_t)2621440)     // bf16 [B][N][64]  = 524288 f
#define OFF_QL  ((size_t)3145728)     // f32  [B][N][192] = 3145728 f (ends 6291456)
#define OFF_HT  ((size_t)2097152)     // bf16 [B][N][C], overlays QB/KB/QL-head (dead after k_attn)
#define OFF_VB  ((size_t)6291456)     // bf16 [B][DV][N]  = 2097152 f
#define OFF_ATT ((size_t)8388608)     // bf16 [B][N][N]   = 8388608 f (transposed [b][m][n])
#define OFF_T   ((size_t)8388608)     // f32  [B][C][N], overlays ATT (dead after k_pv)
#define OFF_WQK ((size_t)16777216)    // bf16 [128][256]
#define OFF_WV  ((size_t)16793600)    // bf16 [256][256]
#define OFF_WT  ((size_t)16826368)    // bf16 [256][256]
#define OFF_BNS ((size_t)16859136)
#define OFF_BNQ ((size_t)16859392)
// total 16859648 f = 67.4 MB

typedef __attribute__((ext_vector_type(8))) short short8;
typedef __attribute__((ext_vector_type(4))) float f32x4;

__device__ __forceinline__ unsigned short f2b(float f) {
    unsigned int u = __float_as_uint(f);
    u = u + 0x7fffu + ((u >> 16) & 1u);      // RNE
    return (unsigned short)(u >> 16);
}
__device__ __forceinline__ float b2f(unsigned short s) {
    return __uint_as_float(((unsigned int)s) << 16);
}

// ---------------------------------------------------------------------------
// K0: convert weights to bf16. Wqk = [qw;kw] (128x256), Wv (256x256), Wt (256x256)
__global__ __launch_bounds__(256) void k_prep(
    const float* __restrict__ qw, const float* __restrict__ kw,
    const float* __restrict__ vw, const float* __restrict__ tw,
    unsigned short* __restrict__ Wqk, unsigned short* __restrict__ Wv,
    unsigned short* __restrict__ Wt)
{
    const int o = blockIdx.x * 256 + threadIdx.x;   // quad index, 40960 total
    const float* src; unsigned short* dst;
    if (o < 8192) {
        const int e = o * 4;
        src = (e < 16384) ? (qw + e) : (kw + e - 16384);
        dst = Wqk + e;
    } else if (o < 24576) {
        const int e = (o - 8192) * 4;
        src = vw + e; dst = Wv + e;
    } else {
        const int e = (o - 24576) * 4;
        src = tw + e; dst = Wt + e;
    }
    const float4 v = *(const float4*)src;
    ushort4 u;
    u.x = f2b(v.x); u.y = f2b(v.y); u.z = f2b(v.z); u.w = f2b(v.w);
    *(ushort4*)dst = u;
}

// ---------------------------------------------------------------------------
// K0b: x f32 [b][c][n] -> xT bf16 [b][n][c].  Pad 68 keeps rows 16B-aligned.
__global__ __launch_bounds__(256) void k_xt(
    const float* __restrict__ x, unsigned short* __restrict__ xT)
{
    __shared__ float tile[64][68];
    const int b = blockIdx.z;
    const int c0 = blockIdx.y * 64;
    const int n0 = blockIdx.x * 64;
    const int tid = threadIdx.x;
    #pragma unroll
    for (int it = 0; it < 4; ++it) {
        const int r = it * 16 + (tid >> 4);
        const int c4 = (tid & 15) * 4;
        *(float4*)&tile[r][c4] =
            *(const float4*)(x + ((size_t)b * CC + c0 + r) * NN + n0 + c4);
    }
    __syncthreads();
    const int n = tid >> 2;
    const int cg = (tid & 3) * 16;
    alignas(16) unsigned short buf[16];
    #pragma unroll
    for (int j = 0; j < 16; ++j) buf[j] = f2b(tile[cg + j][n]);
    unsigned short* dst = xT + ((size_t)b * NN + n0 + n) * CC + c0 + cg;
    *(short8*)dst       = *(const short8*)&buf[0];
    *(short8*)(dst + 8) = *(const short8*)&buf[8];
}

// ---------------------------------------------------------------------------
// K1: Q,K projection via MFMA. D[n][ch]: A=xT rows (n), B=Wqk rows (ch).
__global__ __launch_bounds__(256) void k_projqk(
    const unsigned short* __restrict__ xT, const unsigned short* __restrict__ Wqk,
    unsigned short* __restrict__ Qb, unsigned short* __restrict__ Kb)
{
    const int b = blockIdx.y;
    const int n0 = blockIdx.x * 32;
    const int tid = threadIdx.x;
    const int l = tid & 63, w = tid >> 6;
    const int l15 = l & 15, l4 = l >> 4;
    const int ng = (w >> 1) * 16, wh = (w & 1) * 64;
    const unsigned short* ap = xT + ((size_t)b * NN + n0 + ng + l15) * CC + l4 * 8;
    const unsigned short* bp = Wqk + ((size_t)(wh + l15)) * CC + l4 * 8;
    f32x4 z = {0.f, 0.f, 0.f, 0.f};
    f32x4 acc[4] = {z, z, z, z};
    #pragma unroll 2
    for (int kk = 0; kk < CC; kk += 32) {
        const short8 a = *(const short8*)(ap + kk);
        short8 bf[4];
        #pragma unroll
        for (int j = 0; j < 4; ++j)
            bf[j] = *(const short8*)(bp + (size_t)j * 16 * CC + kk);
        #pragma unroll
        for (int j = 0; j < 4; ++j)
            acc[j] = __builtin_amdgcn_mfma_f32_16x16x32_bf16(a, bf[j], acc[j], 0, 0, 0);
    }
    #pragma unroll
    for (int j = 0; j < 4; ++j)
        #pragma unroll
        for (int r = 0; r < 4; ++r) {
            const int n = n0 + ng + l4 * 4 + r;
            const int ch = wh + j * 16 + l15;
            const unsigned short v = f2b(acc[j][r]);
            if (ch < 64) Qb[((size_t)b * NN + n) * DQK_ + ch] = v;
            else         Kb[((size_t)b * NN + n) * DQK_ + ch - 64] = v;
        }
}

// ---------------------------------------------------------------------------
// K1b: QL[b][n][a*64+q] = sum_d Q[n][d] * lt_a[q][d]  (fp32 out, bf16 Q in)
__global__ __launch_bounds__(256) void k_ql(
    const unsigned short* __restrict__ Qb, const float* __restrict__ xlt,
    const float* __restrict__ ylt, const float* __restrict__ zlt,
    float* __restrict__ QL)
{
    __shared__ float QsT[64][68];    // [d][n]
    __shared__ float LTt[64][196];   // [d][a*64+q]
    const int b = blockIdx.y;
    const int n0 = blockIdx.x * 64;
    const int tid = threadIdx.x;
    #pragma unroll
    for (int it = 0; it < 4; ++it) {
        const int i4 = it * 256 + tid;
        const int r  = i4 >> 4;
        const int d4 = (i4 & 15) * 4;
        const ushort4 q4 = *(const ushort4*)(Qb + ((size_t)b * NN + n0 + r) * DQK_ + d4);
        QsT[d4 + 0][r] = b2f(q4.x); QsT[d4 + 1][r] = b2f(q4.y);
        QsT[d4 + 2][r] = b2f(q4.z); QsT[d4 + 3][r] = b2f(q4.w);
    }
    for (int o = tid; o < 12288; o += 256) {
        const int a = o >> 12, rem = o & 4095, q = rem >> 6, d = rem & 63;
        const float* lt = (a == 0) ? xlt : ((a == 1) ? ylt : zlt);
        LTt[d][a * 64 + q] = (q < 63) ? lt[q * 64 + d] : 0.0f;
    }
    __syncthreads();
    const int tn2 = (tid & 15) * 4;
    const int ta  = (tid >> 4) * 12;
    float acc[4][12] = {};
    for (int d = 0; d < 64; ++d) {
        float4 qv = *(float4*)&QsT[d][tn2];
        const float* qp = (const float*)&qv;
        #pragma unroll
        for (int j3 = 0; j3 < 3; ++j3) {
            float4 lv = *(float4*)&LTt[d][ta + j3 * 4];
            const float* lp = (const float*)&lv;
            #pragma unroll
            for (int i = 0; i < 4; ++i)
                #pragma unroll
                for (int jj = 0; jj < 4; ++jj)
                    acc[i][j3 * 4 + jj] += qp[i] * lp[jj];
        }
    }
    #pragma unroll
    for (int i = 0; i < 4; ++i)
        #pragma unroll
        for (int j3 = 0; j3 < 3; ++j3) {
            float4 o4;
            o4.x = acc[i][j3 * 4 + 0]; o4.y = acc[i][j3 * 4 + 1];
            o4.z = acc[i][j3 * 4 + 2]; o4.w = acc[i][j3 * 4 + 3];
            *(float4*)(QL + ((size_t)b * NN + n0 + tn2 + i) * NR + ta + j3 * 4) = o4;
        }
}

// ---------------------------------------------------------------------------
// K2: V projection via MFMA. D[dv][n]: A=Wv rows (dv), B=xT rows (n).
__global__ __launch_bounds__(256) void k_projv(
    const unsigned short* __restrict__ Wv, const unsigned short* __restrict__ xT,
    const float* __restrict__ vb, unsigned short* __restrict__ Vb)
{
    const int b = blockIdx.y;
    const int n0 = blockIdx.x * 32;
    const int tid = threadIdx.x;
    const int l = tid & 63, w = tid >> 6;
    const int l15 = l & 15, l4 = l >> 4;
    const unsigned short* ap = Wv + ((size_t)(w * 64 + l15)) * CC + l4 * 8;
    const unsigned short* bp = xT + ((size_t)b * NN + n0 + l15) * CC + l4 * 8;
    f32x4 z = {0.f, 0.f, 0.f, 0.f};
    f32x4 acc[4][2] = {{z, z}, {z, z}, {z, z}, {z, z}};
    #pragma unroll 2
    for (int kk = 0; kk < CC; kk += 32) {
        short8 af[4], bf[2];
        #pragma unroll
        for (int i = 0; i < 4; ++i)
            af[i] = *(const short8*)(ap + (size_t)i * 16 * CC + kk);
        #pragma unroll
        for (int j = 0; j < 2; ++j)
            bf[j] = *(const short8*)(bp + (size_t)j * 16 * CC + kk);
        #pragma unroll
        for (int i = 0; i < 4; ++i)
            #pragma unroll
            for (int j = 0; j < 2; ++j)
                acc[i][j] = __builtin_amdgcn_mfma_f32_16x16x32_bf16(af[i], bf[j], acc[i][j], 0, 0, 0);
    }
    #pragma unroll
    for (int i = 0; i < 4; ++i)
        #pragma unroll
        for (int r = 0; r < 4; ++r) {
            const int dv = w * 64 + i * 16 + l4 * 4 + r;
            const float bias = vb[dv];
            #pragma unroll
            for (int j = 0; j < 2; ++j) {
                const int n = n0 + j * 16 + l15;
                Vb[((size_t)b * DV_ + dv) * NN + n] = f2b(acc[i][j][r] + bias);
            }
        }
}

// ---------------------------------------------------------------------------
// K3: energy (MFMA, swapped operands) + rel gathers + softmax -> ATT_T bf16.
__global__ __launch_bounds__(256) void k_attn(
    const unsigned short* __restrict__ Qb, const unsigned short* __restrict__ Kb,
    const float* __restrict__ QL, const int* __restrict__ disc,
    unsigned short* __restrict__ att)
{
    __shared__ float QLs[16][193];
    __shared__ int   dmlT[3][1024];
    __shared__ float redM[4][16];
    __shared__ float redS[4][16];
    const int b = blockIdx.y;
    const int q0 = blockIdx.x * 16;
    const int tid = threadIdx.x;
    const int l = tid & 63, w = tid >> 6;
    const int l15 = l & 15, l4 = l >> 4;

    for (int o = tid; o < 16 * NR; o += 256) {
        const int r = o / NR, c = o - r * NR;
        QLs[r][c] = QL[((size_t)b * NN + q0 + r) * NR + c];
    }
    for (int o = tid; o < 3 * NN; o += 256) {
        const int a = o >> 10, m = o & 1023;
        dmlT[a][m] = disc[((size_t)b * NN + m) * 3 + a];
    }
    __syncthreads();

    const int q = q0 + l15;
    const int dn0 = disc[((size_t)b * NN + q) * 3 + 0];
    const int dn1 = disc[((size_t)b * NN + q) * 3 + 1];
    const int dn2 = disc[((size_t)b * NN + q) * 3 + 2];

    const unsigned short* qp = Qb + ((size_t)b * NN + q) * DQK_ + l4 * 8;
    const short8 qf0 = *(const short8*)qp;
    const short8 qf1 = *(const short8*)(qp + 32);

    float s[64];
    #pragma unroll
    for (int t = 0; t < 16; ++t) {
        const int m0 = t * 64 + w * 16;
        const unsigned short* kp = Kb + ((size_t)b * NN + m0 + l15) * DQK_ + l4 * 8;
        const short8 kf0 = *(const short8*)kp;
        const short8 kf1 = *(const short8*)(kp + 32);
        f32x4 acc = {0.f, 0.f, 0.f, 0.f};
        acc = __builtin_amdgcn_mfma_f32_16x16x32_bf16(kf0, qf0, acc, 0, 0, 0);
        acc = __builtin_amdgcn_mfma_f32_16x16x32_bf16(kf1, qf1, acc, 0, 0, 0);
        #pragma unroll
        for (int r = 0; r < 4; ++r) {
            const int m = m0 + l4 * 4 + r;
            const int i0 = dmlT[0][m] - dn0 + 31;
            const int i1 = dmlT[1][m] - dn1 + 31;
            const int i2 = dmlT[2][m] - dn2 + 31;
            const float rel = QLs[l15][i0] + QLs[l15][64 + i1] + QLs[l15][128 + i2];
            s[t * 4 + r] = (acc[r] + rel) * 0.03125f;
        }
    }

    float mx = -1e30f;
    #pragma unroll
    for (int i = 0; i < 64; ++i) mx = fmaxf(mx, s[i]);
    mx = fmaxf(mx, __shfl_xor(mx, 16));
    mx = fmaxf(mx, __shfl_xor(mx, 32));
    if (l < 16) redM[w][l] = mx;
    __syncthreads();
    mx = fmaxf(fmaxf(redM[0][l15], redM[1][l15]), fmaxf(redM[2][l15], redM[3][l15]));

    float sum = 0.f;
    #pragma unroll
    for (int i = 0; i < 64; ++i) { s[i] = __expf(s[i] - mx); sum += s[i]; }
    sum += __shfl_xor(sum, 16);
    sum += __shfl_xor(sum, 32);
    if (l < 16) redS[w][l] = sum;
    __syncthreads();
    const float inv = 1.0f /
        (redS[0][l15] + redS[1][l15] + redS[2][l15] + redS[3][l15]);

    #pragma unroll
    for (int t = 0; t < 16; ++t)
        #pragma unroll
        for (int r = 0; r < 4; ++r) {
            const int m = t * 64 + w * 16 + l4 * 4 + r;
            att[((size_t)b * NN + m) * NN + q] = f2b(s[t * 4 + r] * inv);
        }
}

// ---------------------------------------------------------------------------
// K4: XR^T[m][dv] = sum_n ATT_T[m][n] V[dv][n]; fused H^T = x^T - XR^T (bf16).
__global__ __launch_bounds__(256) void k_pv(
    const unsigned short* __restrict__ att, const unsigned short* __restrict__ Vb,
    const unsigned short* __restrict__ xT, unsigned short* __restrict__ HT)
{
    const int b = blockIdx.z;
    const int d0 = blockIdx.y * 64;
    const int m0 = blockIdx.x * 128;
    const int tid = threadIdx.x;
    const int l = tid & 63, w = tid >> 6;
    const int l15 = l & 15, l4 = l >> 4;
    const int wm = (w & 1) * 64, wd = (w >> 1) * 32;
    const unsigned short* ap = att + ((size_t)b * NN + m0 + wm + l15) * NN + l4 * 8;
    const unsigned short* bp = Vb + ((size_t)b * DV_ + d0 + wd + l15) * NN + l4 * 8;
    f32x4 z = {0.f, 0.f, 0.f, 0.f};
    f32x4 acc[4][2] = {{z, z}, {z, z}, {z, z}, {z, z}};
    #pragma unroll 2
    for (int nk = 0; nk < NN; nk += 32) {
        short8 af[4], bf[2];
        #pragma unroll
        for (int i = 0; i < 4; ++i)
            af[i] = *(const short8*)(ap + (size_t)i * 16 * NN + nk);
        #pragma unroll
        for (int j = 0; j < 2; ++j)
            bf[j] = *(const short8*)(bp + (size_t)j * 16 * NN + nk);
        #pragma unroll
        for (int i = 0; i < 4; ++i)
            #pragma unroll
            for (int j = 0; j < 2; ++j)
                acc[i][j] = __builtin_amdgcn_mfma_f32_16x16x32_bf16(af[i], bf[j], acc[i][j], 0, 0, 0);
    }
    #pragma unroll
    for (int i = 0; i < 4; ++i)
        #pragma unroll
        for (int r = 0; r < 4; ++r) {
            const int m = m0 + wm + i * 16 + l4 * 4 + r;
            const unsigned short* xrow = xT + ((size_t)b * NN + m) * CC;
            unsigned short* hrow = HT + ((size_t)b * NN + m) * CC;
            #pragma unroll
            for (int j = 0; j < 2; ++j) {
                const int dv = d0 + wd + j * 16 + l15;
                hrow[dv] = f2b(b2f(xrow[dv]) - acc[i][j][r]);
            }
        }
}

// ---------------------------------------------------------------------------
// K5: T[c][n] = sum_d Wt[c][d] H^T[n][d] + tb; BN partial sums.
__global__ __launch_bounds__(256) void k_trans(
    const unsigned short* __restrict__ Wt, const unsigned short* __restrict__ HT,
    const float* __restrict__ tb, float* __restrict__ T,
    float* __restrict__ bnS, float* __restrict__ bnQ)
{
    __shared__ float sS[128], sQ[128];
    const int b = blockIdx.z;
    const int c0 = blockIdx.y * 128;
    const int n0 = blockIdx.x * 64;
    const int tid = threadIdx.x;
    const int l = tid & 63, w = tid >> 6;
    const int l15 = l & 15, l4 = l >> 4;
    const int wc = (w & 1) * 64, wn = (w >> 1) * 32;
    if (tid < 128) { sS[tid] = 0.f; sQ[tid] = 0.f; }
    __syncthreads();
    const unsigned short* ap = Wt + ((size_t)(c0 + wc + l15)) * CC + l4 * 8;
    const unsigned short* bp = HT + ((size_t)b * NN + n0 + wn + l15) * CC + l4 * 8;
    f32x4 z = {0.f, 0.f, 0.f, 0.f};
    f32x4 acc[4][2] = {{z, z}, {z, z}, {z, z}, {z, z}};
    #pragma unroll 2
    for (int kk = 0; kk < CC; kk += 32) {
        short8 af[4], bf[2];
        #pragma unroll
        for (int i = 0; i < 4; ++i)
            af[i] = *(const short8*)(ap + (size_t)i * 16 * CC + kk);
        #pragma unroll
        for (int j = 0; j < 2; ++j)
            bf[j] = *(const short8*)(bp + (size_t)j * 16 * CC + kk);
        #pragma unroll
        for (int i = 0; i < 4; ++i)
            #pragma unroll
            for (int j = 0; j < 2; ++j)
                acc[i][j] = __builtin_amdgcn_mfma_f32_16x16x32_bf16(af[i], bf[j], acc[i][j], 0, 0, 0);
    }
    #pragma unroll
    for (int i = 0; i < 4; ++i)
        #pragma unroll
        for (int r = 0; r < 4; ++r) {
            const int cl = wc + i * 16 + l4 * 4 + r;
            const int c = c0 + cl;
            const float bias = tb[c];
            float s = 0.f, q = 0.f;
            #pragma unroll
            for (int j = 0; j < 2; ++j) {
                const int n = n0 + wn + j * 16 + l15;
                const float t = acc[i][j][r] + bias;
                T[((size_t)b * CC + c) * NN + n] = t;
                s += t; q += t * t;
            }
            s += __shfl_xor(s, 1); s += __shfl_xor(s, 2);
            s += __shfl_xor(s, 4); s += __shfl_xor(s, 8);
            q += __shfl_xor(q, 1); q += __shfl_xor(q, 2);
            q += __shfl_xor(q, 4); q += __shfl_xor(q, 8);
            if (l15 == 0) {
                atomicAdd(&sS[cl], s);
                atomicAdd(&sQ[cl], q);
            }
        }
    __syncthreads();
    if (tid < 128) {
        atomicAdd(&bnS[c0 + tid], sS[tid]);
        atomicAdd(&bnQ[c0 + tid], sQ[tid]);
    }
}

// ---------------------------------------------------------------------------
// K6: out = x + relu(bn(T)).  GRID MUST BE 4096 (= B*C*N/4/256): i4 is a
// float4 index. (16384 here was the round-3/4 crash: 4x OOB on d_out/T/x.)
__global__ __launch_bounds__(256) void k_out(
    const float* __restrict__ x, const float* __restrict__ T,
    const float* __restrict__ gamma, const float* __restrict__ beta,
    const float* __restrict__ bnS, const float* __restrict__ bnQ,
    float* __restrict__ out)
{
    const int i4 = blockIdx.x * 256 + threadIdx.x;
    const int c = (i4 >> 8) & 255;
    const float meanv = bnS[c] * (1.0f / 16384.0f);
    const float varv  = bnQ[c] * (1.0f / 16384.0f) - meanv * meanv;
    const float inv   = rsqrtf(varv + EPS_F);
    const float g = gamma[c] * inv;
    const float be = beta[c];
    const float4 t4 = *(const float4*)(T + (size_t)i4 * 4);
    const float4 x4 = *(const float4*)(x + (size_t)i4 * 4);
    float4 o;
    o.x = x4.x + fmaxf(g * (t4.x - meanv) + be, 0.0f);
    o.y = x4.y + fmaxf(g * (t4.y - meanv) + be, 0.0f);
    o.z = x4.z + fmaxf(g * (t4.z - meanv) + be, 0.0f);
    o.w = x4.w + fmaxf(g * (t4.w - meanv) + be, 0.0f);
    *(float4*)(out + (size_t)i4 * 4) = o;
}

// ---------------------------------------------------------------------------
extern "C" void kernel_launch(void* const* d_in, const int* in_sizes, int n_in,
                              void* d_out, int out_size, void* d_ws, size_t ws_size,
                              hipStream_t stream)
{
    const float* x     = (const float*)d_in[0];
    const int*   disc  = (const int*)d_in[1];
    // d_in[2] = xyz (unused)
    const float* qw    = (const float*)d_in[3];
    const float* kw    = (const float*)d_in[4];
    const float* vw    = (const float*)d_in[5];
    const float* vb    = (const float*)d_in[6];
    const float* tw    = (const float*)d_in[7];
    const float* tb    = (const float*)d_in[8];
    const float* gamma = (const float*)d_in[9];
    const float* beta  = (const float*)d_in[10];
    const float* xlt   = (const float*)d_in[11];
    const float* ylt   = (const float*)d_in[12];
    const float* zlt   = (const float*)d_in[13];
    float* ws  = (float*)d_ws;
    float* out = (float*)d_out;

    unsigned short* xT  = (unsigned short*)(ws + OFF_XT);
    unsigned short* Qb  = (unsigned short*)(ws + OFF_QB);
    unsigned short* Kbf = (unsigned short*)(ws + OFF_KB);
    float*          QL  = ws + OFF_QL;
    unsigned short* HT  = (unsigned short*)(ws + OFF_HT);
    unsigned short* Vb  = (unsigned short*)(ws + OFF_VB);
    unsigned short* ATT = (unsigned short*)(ws + OFF_ATT);
    float*          T   = ws + OFF_T;
    unsigned short* Wqk = (unsigned short*)(ws + OFF_WQK);
    unsigned short* Wv  = (unsigned short*)(ws + OFF_WV);
    unsigned short* Wt  = (unsigned short*)(ws + OFF_WT);
    float*          bnS = ws + OFF_BNS;
    float*          bnQ = ws + OFF_BNQ;

    hipMemsetAsync(bnS, 0, 512 * sizeof(float), stream);

    k_prep  <<<dim3(160), 256, 0, stream>>>(qw, kw, vw, tw, Wqk, Wv, Wt);
    k_xt    <<<dim3(16, 4, 16), 256, 0, stream>>>(x, xT);
    k_projqk<<<dim3(32, 16), 256, 0, stream>>>(xT, Wqk, Qb, Kbf);
    k_ql    <<<dim3(16, 16), 256, 0, stream>>>(Qb, xlt, ylt, zlt, QL);
    k_projv <<<dim3(32, 16), 256, 0, stream>>>(Wv, xT, vb, Vb);
    k_attn  <<<dim3(64, 16), 256, 0, stream>>>(Qb, Kbf, QL, disc, ATT);
    k_pv    <<<dim3(8, 4, 16), 256, 0, stream>>>(ATT, Vb, xT, HT);
    k_trans <<<dim3(16, 2, 16), 256, 0, stream>>>(Wt, HT, tb, T, bnS, bnQ);
    k_out   <<<dim3(4096), 256, 0, stream>>>(x, T, gamma, beta, bnS, bnQ, out);
}

// Round 6
// 173.631 us; speedup vs baseline: 3.0931x; 1.0690x over previous
//
#include <hip/hip_runtime.h>
#include <math.h>

#define BB 16
#define CC 256
#define NN 1024
#define DQK_ 64
#define DV_ 256
#define NR 192          // 3 * 64 (padded 63-entry tables)
#define EPS_F 1e-5f

// workspace offsets (float units)
#define OFF_XT  ((size_t)0)           // bf16 [B][N][C]   = 2097152 f
#define OFF_QB  ((size_t)2097152)     // bf16 [B][N][64]  = 524288 f
#define OFF_KB  ((size_t)2621440)     // bf16 [B][N][64]  = 524288 f
#define OFF_QL  ((size_t)3145728)     // f32  [B][N][192] = 3145728 f (ends 6291456)
#define OFF_HT  ((size_t)2097152)     // bf16 [B][N][C], overlays QB/KB/QL-head (dead after k_attn)
#define OFF_VB  ((size_t)6291456)     // bf16 [B][DV][N]  = 2097152 f
#define OFF_ATT ((size_t)8388608)     // bf16 [B][N][N]   = 8388608 f (transposed [b][m][n])
#define OFF_T   ((size_t)8388608)     // bf16 [B][C][N], overlays ATT (dead after k_pv)
#define OFF_WQK ((size_t)16777216)    // bf16 [128][256]
#define OFF_WV  ((size_t)16793600)    // bf16 [256][256]
#define OFF_WT  ((size_t)16826368)    // bf16 [256][256]
#define OFF_BNS ((size_t)16859136)
#define OFF_BNQ ((size_t)16859392)
// total 16859648 f = 67.4 MB

typedef __attribute__((ext_vector_type(8))) short short8;
typedef __attribute__((ext_vector_type(4))) float f32x4;

__device__ __forceinline__ unsigned short f2b(float f) {
    unsigned int u = __float_as_uint(f);
    u = u + 0x7fffu + ((u >> 16) & 1u);      // RNE
    return (unsigned short)(u >> 16);
}
__device__ __forceinline__ float b2f(unsigned short s) {
    return __uint_as_float(((unsigned int)s) << 16);
}

// ---------------------------------------------------------------------------
// K0: convert weights to bf16. Wqk = [qw;kw] (128x256), Wv (256x256), Wt (256x256)
__global__ __launch_bounds__(256) void k_prep(
    const float* __restrict__ qw, const float* __restrict__ kw,
    const float* __restrict__ vw, const float* __restrict__ tw,
    unsigned short* __restrict__ Wqk, unsigned short* __restrict__ Wv,
    unsigned short* __restrict__ Wt)
{
    const int o = blockIdx.x * 256 + threadIdx.x;   // quad index, 40960 total
    const float* src; unsigned short* dst;
    if (o < 8192) {
        const int e = o * 4;
        src = (e < 16384) ? (qw + e) : (kw + e - 16384);
        dst = Wqk + e;
    } else if (o < 24576) {
        const int e = (o - 8192) * 4;
        src = vw + e; dst = Wv + e;
    } else {
        const int e = (o - 24576) * 4;
        src = tw + e; dst = Wt + e;
    }
    const float4 v = *(const float4*)src;
    ushort4 u;
    u.x = f2b(v.x); u.y = f2b(v.y); u.z = f2b(v.z); u.w = f2b(v.w);
    *(ushort4*)dst = u;
}

// ---------------------------------------------------------------------------
// K0b: x f32 [b][c][n] -> xT bf16 [b][n][c].  Pad 68 keeps rows 16B-aligned.
__global__ __launch_bounds__(256) void k_xt(
    const float* __restrict__ x, unsigned short* __restrict__ xT)
{
    __shared__ float tile[64][68];
    const int b = blockIdx.z;
    const int c0 = blockIdx.y * 64;
    const int n0 = blockIdx.x * 64;
    const int tid = threadIdx.x;
    #pragma unroll
    for (int it = 0; it < 4; ++it) {
        const int r = it * 16 + (tid >> 4);
        const int c4 = (tid & 15) * 4;
        *(float4*)&tile[r][c4] =
            *(const float4*)(x + ((size_t)b * CC + c0 + r) * NN + n0 + c4);
    }
    __syncthreads();
    const int n = tid >> 2;
    const int cg = (tid & 3) * 16;
    alignas(16) unsigned short buf[16];
    #pragma unroll
    for (int j = 0; j < 16; ++j) buf[j] = f2b(tile[cg + j][n]);
    unsigned short* dst = xT + ((size_t)b * NN + n0 + n) * CC + c0 + cg;
    *(short8*)dst       = *(const short8*)&buf[0];
    *(short8*)(dst + 8) = *(const short8*)&buf[8];
}

// ---------------------------------------------------------------------------
// K1: Q,K projection via MFMA. D[n][ch]: A=xT rows (n), B=Wqk rows (ch).
__global__ __launch_bounds__(256) void k_projqk(
    const unsigned short* __restrict__ xT, const unsigned short* __restrict__ Wqk,
    unsigned short* __restrict__ Qb, unsigned short* __restrict__ Kb)
{
    const int b = blockIdx.y;
    const int n0 = blockIdx.x * 32;
    const int tid = threadIdx.x;
    const int l = tid & 63, w = tid >> 6;
    const int l15 = l & 15, l4 = l >> 4;
    const int ng = (w >> 1) * 16, wh = (w & 1) * 64;
    const unsigned short* ap = xT + ((size_t)b * NN + n0 + ng + l15) * CC + l4 * 8;
    const unsigned short* bp = Wqk + ((size_t)(wh + l15)) * CC + l4 * 8;
    f32x4 z = {0.f, 0.f, 0.f, 0.f};
    f32x4 acc[4] = {z, z, z, z};
    #pragma unroll 2
    for (int kk = 0; kk < CC; kk += 32) {
        const short8 a = *(const short8*)(ap + kk);
        short8 bf[4];
        #pragma unroll
        for (int j = 0; j < 4; ++j)
            bf[j] = *(const short8*)(bp + (size_t)j * 16 * CC + kk);
        #pragma unroll
        for (int j = 0; j < 4; ++j)
            acc[j] = __builtin_amdgcn_mfma_f32_16x16x32_bf16(a, bf[j], acc[j], 0, 0, 0);
    }
    #pragma unroll
    for (int j = 0; j < 4; ++j)
        #pragma unroll
        for (int r = 0; r < 4; ++r) {
            const int n = n0 + ng + l4 * 4 + r;
            const int ch = wh + j * 16 + l15;
            const unsigned short v = f2b(acc[j][r]);
            if (ch < 64) Qb[((size_t)b * NN + n) * DQK_ + ch] = v;
            else         Kb[((size_t)b * NN + n) * DQK_ + ch - 64] = v;
        }
}

// ---------------------------------------------------------------------------
// K1b: QL[b][n][a*64+q] = sum_d Q[n][d] * lt_a[q][d]  (fp32 out, bf16 Q in)
__global__ __launch_bounds__(256) void k_ql(
    const unsigned short* __restrict__ Qb, const float* __restrict__ xlt,
    const float* __restrict__ ylt, const float* __restrict__ zlt,
    float* __restrict__ QL)
{
    __shared__ float QsT[64][68];    // [d][n]
    __shared__ float LTt[64][196];   // [d][a*64+q]
    const int b = blockIdx.y;
    const int n0 = blockIdx.x * 64;
    const int tid = threadIdx.x;
    #pragma unroll
    for (int it = 0; it < 4; ++it) {
        const int i4 = it * 256 + tid;
        const int r  = i4 >> 4;
        const int d4 = (i4 & 15) * 4;
        const ushort4 q4 = *(const ushort4*)(Qb + ((size_t)b * NN + n0 + r) * DQK_ + d4);
        QsT[d4 + 0][r] = b2f(q4.x); QsT[d4 + 1][r] = b2f(q4.y);
        QsT[d4 + 2][r] = b2f(q4.z); QsT[d4 + 3][r] = b2f(q4.w);
    }
    for (int o = tid; o < 12288; o += 256) {
        const int a = o >> 12, rem = o & 4095, q = rem >> 6, d = rem & 63;
        const float* lt = (a == 0) ? xlt : ((a == 1) ? ylt : zlt);
        LTt[d][a * 64 + q] = (q < 63) ? lt[q * 64 + d] : 0.0f;
    }
    __syncthreads();
    const int tn2 = (tid & 15) * 4;
    const int ta  = (tid >> 4) * 12;
    float acc[4][12] = {};
    for (int d = 0; d < 64; ++d) {
        float4 qv = *(float4*)&QsT[d][tn2];
        const float* qp = (const float*)&qv;
        #pragma unroll
        for (int j3 = 0; j3 < 3; ++j3) {
            float4 lv = *(float4*)&LTt[d][ta + j3 * 4];
            const float* lp = (const float*)&lv;
            #pragma unroll
            for (int i = 0; i < 4; ++i)
                #pragma unroll
                for (int jj = 0; jj < 4; ++jj)
                    acc[i][j3 * 4 + jj] += qp[i] * lp[jj];
        }
    }
    #pragma unroll
    for (int i = 0; i < 4; ++i)
        #pragma unroll
        for (int j3 = 0; j3 < 3; ++j3) {
            float4 o4;
            o4.x = acc[i][j3 * 4 + 0]; o4.y = acc[i][j3 * 4 + 1];
            o4.z = acc[i][j3 * 4 + 2]; o4.w = acc[i][j3 * 4 + 3];
            *(float4*)(QL + ((size_t)b * NN + n0 + tn2 + i) * NR + ta + j3 * 4) = o4;
        }
}

// ---------------------------------------------------------------------------
// K2: V projection via MFMA. D[dv][n]: A=Wv rows (dv), B=xT rows (n).
__global__ __launch_bounds__(256) void k_projv(
    const unsigned short* __restrict__ Wv, const unsigned short* __restrict__ xT,
    const float* __restrict__ vb, unsigned short* __restrict__ Vb)
{
    const int b = blockIdx.y;
    const int n0 = blockIdx.x * 32;
    const int tid = threadIdx.x;
    const int l = tid & 63, w = tid >> 6;
    const int l15 = l & 15, l4 = l >> 4;
    const unsigned short* ap = Wv + ((size_t)(w * 64 + l15)) * CC + l4 * 8;
    const unsigned short* bp = xT + ((size_t)b * NN + n0 + l15) * CC + l4 * 8;
    f32x4 z = {0.f, 0.f, 0.f, 0.f};
    f32x4 acc[4][2] = {{z, z}, {z, z}, {z, z}, {z, z}};
    #pragma unroll 2
    for (int kk = 0; kk < CC; kk += 32) {
        short8 af[4], bf[2];
        #pragma unroll
        for (int i = 0; i < 4; ++i)
            af[i] = *(const short8*)(ap + (size_t)i * 16 * CC + kk);
        #pragma unroll
        for (int j = 0; j < 2; ++j)
            bf[j] = *(const short8*)(bp + (size_t)j * 16 * CC + kk);
        #pragma unroll
        for (int i = 0; i < 4; ++i)
            #pragma unroll
            for (int j = 0; j < 2; ++j)
                acc[i][j] = __builtin_amdgcn_mfma_f32_16x16x32_bf16(af[i], bf[j], acc[i][j], 0, 0, 0);
    }
    #pragma unroll
    for (int i = 0; i < 4; ++i)
        #pragma unroll
        for (int r = 0; r < 4; ++r) {
            const int dv = w * 64 + i * 16 + l4 * 4 + r;
            const float bias = vb[dv];
            #pragma unroll
            for (int j = 0; j < 2; ++j) {
                const int n = n0 + j * 16 + l15;
                Vb[((size_t)b * DV_ + dv) * NN + n] = f2b(acc[i][j][r] + bias);
            }
        }
}

// ---------------------------------------------------------------------------
// K3: energy (MFMA, swapped operands) + rel gathers + softmax -> ATT_T bf16.
__global__ __launch_bounds__(256) void k_attn(
    const unsigned short* __restrict__ Qb, const unsigned short* __restrict__ Kb,
    const float* __restrict__ QL, const int* __restrict__ disc,
    unsigned short* __restrict__ att)
{
    __shared__ float QLs[16][193];
    __shared__ int   dmlT[3][1024];
    __shared__ float redM[4][16];
    __shared__ float redS[4][16];
    const int b = blockIdx.y;
    const int q0 = blockIdx.x * 16;
    const int tid = threadIdx.x;
    const int l = tid & 63, w = tid >> 6;
    const int l15 = l & 15, l4 = l >> 4;

    for (int o = tid; o < 16 * NR; o += 256) {
        const int r = o / NR, c = o - r * NR;
        QLs[r][c] = QL[((size_t)b * NN + q0 + r) * NR + c];
    }
    for (int o = tid; o < 3 * NN; o += 256) {
        const int a = o >> 10, m = o & 1023;
        dmlT[a][m] = disc[((size_t)b * NN + m) * 3 + a];
    }
    __syncthreads();

    const int q = q0 + l15;
    const int dn0 = disc[((size_t)b * NN + q) * 3 + 0];
    const int dn1 = disc[((size_t)b * NN + q) * 3 + 1];
    const int dn2 = disc[((size_t)b * NN + q) * 3 + 2];

    const unsigned short* qp = Qb + ((size_t)b * NN + q) * DQK_ + l4 * 8;
    const short8 qf0 = *(const short8*)qp;
    const short8 qf1 = *(const short8*)(qp + 32);

    float s[64];
    #pragma unroll
    for (int t = 0; t < 16; ++t) {
        const int m0 = t * 64 + w * 16;
        const unsigned short* kp = Kb + ((size_t)b * NN + m0 + l15) * DQK_ + l4 * 8;
        const short8 kf0 = *(const short8*)kp;
        const short8 kf1 = *(const short8*)(kp + 32);
        f32x4 acc = {0.f, 0.f, 0.f, 0.f};
        acc = __builtin_amdgcn_mfma_f32_16x16x32_bf16(kf0, qf0, acc, 0, 0, 0);
        acc = __builtin_amdgcn_mfma_f32_16x16x32_bf16(kf1, qf1, acc, 0, 0, 0);
        #pragma unroll
        for (int r = 0; r < 4; ++r) {
            const int m = m0 + l4 * 4 + r;
            const int i0 = dmlT[0][m] - dn0 + 31;
            const int i1 = dmlT[1][m] - dn1 + 31;
            const int i2 = dmlT[2][m] - dn2 + 31;
            const float rel = QLs[l15][i0] + QLs[l15][64 + i1] + QLs[l15][128 + i2];
            s[t * 4 + r] = (acc[r] + rel) * 0.03125f;
        }
    }

    float mx = -1e30f;
    #pragma unroll
    for (int i = 0; i < 64; ++i) mx = fmaxf(mx, s[i]);
    mx = fmaxf(mx, __shfl_xor(mx, 16));
    mx = fmaxf(mx, __shfl_xor(mx, 32));
    if (l < 16) redM[w][l] = mx;
    __syncthreads();
    mx = fmaxf(fmaxf(redM[0][l15], redM[1][l15]), fmaxf(redM[2][l15], redM[3][l15]));

    float sum = 0.f;
    #pragma unroll
    for (int i = 0; i < 64; ++i) { s[i] = __expf(s[i] - mx); sum += s[i]; }
    sum += __shfl_xor(sum, 16);
    sum += __shfl_xor(sum, 32);
    if (l < 16) redS[w][l] = sum;
    __syncthreads();
    const float inv = 1.0f /
        (redS[0][l15] + redS[1][l15] + redS[2][l15] + redS[3][l15]);

    #pragma unroll
    for (int t = 0; t < 16; ++t)
        #pragma unroll
        for (int r = 0; r < 4; ++r) {
            const int m = t * 64 + w * 16 + l4 * 4 + r;
            att[((size_t)b * NN + m) * NN + q] = f2b(s[t * 4 + r] * inv);
        }
}

// ---------------------------------------------------------------------------
// K4: XR^T[m][dv] = sum_n ATT_T[m][n] V[dv][n]; fused H^T = x^T - XR^T (bf16).
// Wave tile 64m x 64d (16 MFMA / 8 loads); block 2x2 waves = 128x128;
// explicit 2-buffer register prefetch to hide L2 latency.
__global__ __launch_bounds__(256) void k_pv(
    const unsigned short* __restrict__ att, const unsigned short* __restrict__ Vb,
    const unsigned short* __restrict__ xT, unsigned short* __restrict__ HT)
{
    const int b = blockIdx.z;
    const int d0 = blockIdx.y * 128;
    const int m0 = blockIdx.x * 128;
    const int tid = threadIdx.x;
    const int l = tid & 63, w = tid >> 6;
    const int l15 = l & 15, l4 = l >> 4;
    const int wm = (w & 1) * 64, wd = (w >> 1) * 64;
    const unsigned short* ap = att + ((size_t)b * NN + m0 + wm + l15) * NN + l4 * 8;
    const unsigned short* bp = Vb + ((size_t)b * DV_ + d0 + wd + l15) * NN + l4 * 8;
    f32x4 z = {0.f, 0.f, 0.f, 0.f};
    f32x4 acc[4][4];
    #pragma unroll
    for (int i = 0; i < 4; ++i)
        #pragma unroll
        for (int j = 0; j < 4; ++j) acc[i][j] = z;

    short8 aA[4], bA[4], aB[4], bB[4];
    #pragma unroll
    for (int i = 0; i < 4; ++i) {
        aA[i] = *(const short8*)(ap + (size_t)i * 16 * NN);
        bA[i] = *(const short8*)(bp + (size_t)i * 16 * NN);
    }
    for (int nk = 0; nk < NN; nk += 64) {
        #pragma unroll
        for (int i = 0; i < 4; ++i) {
            aB[i] = *(const short8*)(ap + (size_t)i * 16 * NN + nk + 32);
            bB[i] = *(const short8*)(bp + (size_t)i * 16 * NN + nk + 32);
        }
        #pragma unroll
        for (int i = 0; i < 4; ++i)
            #pragma unroll
            for (int j = 0; j < 4; ++j)
                acc[i][j] = __builtin_amdgcn_mfma_f32_16x16x32_bf16(aA[i], bA[j], acc[i][j], 0, 0, 0);
        if (nk + 64 < NN) {
            #pragma unroll
            for (int i = 0; i < 4; ++i) {
                aA[i] = *(const short8*)(ap + (size_t)i * 16 * NN + nk + 64);
                bA[i] = *(const short8*)(bp + (size_t)i * 16 * NN + nk + 64);
            }
        }
        #pragma unroll
        for (int i = 0; i < 4; ++i)
            #pragma unroll
            for (int j = 0; j < 4; ++j)
                acc[i][j] = __builtin_amdgcn_mfma_f32_16x16x32_bf16(aB[i], bB[j], acc[i][j], 0, 0, 0);
    }
    #pragma unroll
    for (int i = 0; i < 4; ++i)
        #pragma unroll
        for (int r = 0; r < 4; ++r) {
            const int m = m0 + wm + i * 16 + l4 * 4 + r;
            const unsigned short* xrow = xT + ((size_t)b * NN + m) * CC;
            unsigned short* hrow = HT + ((size_t)b * NN + m) * CC;
            #pragma unroll
            for (int j = 0; j < 4; ++j) {
                const int dv = d0 + wd + j * 16 + l15;
                hrow[dv] = f2b(b2f(xrow[dv]) - acc[i][j][r]);
            }
        }
}

// ---------------------------------------------------------------------------
// K5: T[c][n] (bf16) = sum_d Wt[c][d] H^T[n][d] + tb; BN partial sums (f32).
__global__ __launch_bounds__(256) void k_trans(
    const unsigned short* __restrict__ Wt, const unsigned short* __restrict__ HT,
    const float* __restrict__ tb, unsigned short* __restrict__ T,
    float* __restrict__ bnS, float* __restrict__ bnQ)
{
    __shared__ float sS[128], sQ[128];
    const int b = blockIdx.z;
    const int c0 = blockIdx.y * 128;
    const int n0 = blockIdx.x * 64;
    const int tid = threadIdx.x;
    const int l = tid & 63, w = tid >> 6;
    const int l15 = l & 15, l4 = l >> 4;
    const int wc = (w & 1) * 64, wn = (w >> 1) * 32;
    if (tid < 128) { sS[tid] = 0.f; sQ[tid] = 0.f; }
    __syncthreads();
    const unsigned short* ap = Wt + ((size_t)(c0 + wc + l15)) * CC + l4 * 8;
    const unsigned short* bp = HT + ((size_t)b * NN + n0 + wn + l15) * CC + l4 * 8;
    f32x4 z = {0.f, 0.f, 0.f, 0.f};
    f32x4 acc[4][2] = {{z, z}, {z, z}, {z, z}, {z, z}};
    #pragma unroll 2
    for (int kk = 0; kk < CC; kk += 32) {
        short8 af[4], bf[2];
        #pragma unroll
        for (int i = 0; i < 4; ++i)
            af[i] = *(const short8*)(ap + (size_t)i * 16 * CC + kk);
        #pragma unroll
        for (int j = 0; j < 2; ++j)
            bf[j] = *(const short8*)(bp + (size_t)j * 16 * CC + kk);
        #pragma unroll
        for (int i = 0; i < 4; ++i)
            #pragma unroll
            for (int j = 0; j < 2; ++j)
                acc[i][j] = __builtin_amdgcn_mfma_f32_16x16x32_bf16(af[i], bf[j], acc[i][j], 0, 0, 0);
    }
    #pragma unroll
    for (int i = 0; i < 4; ++i)
        #pragma unroll
        for (int r = 0; r < 4; ++r) {
            const int cl = wc + i * 16 + l4 * 4 + r;
            const int c = c0 + cl;
            const float bias = tb[c];
            float s = 0.f, q = 0.f;
            #pragma unroll
            for (int j = 0; j < 2; ++j) {
                const int n = n0 + wn + j * 16 + l15;
                const float t = acc[i][j][r] + bias;
                T[((size_t)b * CC + c) * NN + n] = f2b(t);
                s += t; q += t * t;
            }
            s += __shfl_xor(s, 1); s += __shfl_xor(s, 2);
            s += __shfl_xor(s, 4); s += __shfl_xor(s, 8);
            q += __shfl_xor(q, 1); q += __shfl_xor(q, 2);
            q += __shfl_xor(q, 4); q += __shfl_xor(q, 8);
            if (l15 == 0) {
                atomicAdd(&sS[cl], s);
                atomicAdd(&sQ[cl], q);
            }
        }
    __syncthreads();
    if (tid < 128) {
        atomicAdd(&bnS[c0 + tid], sS[tid]);
        atomicAdd(&bnQ[c0 + tid], sQ[tid]);
    }
}

// ---------------------------------------------------------------------------
// K6: out = x + relu(bn(T)).  8 elems/thread; grid = B*C*N/8/256 = 2048.
__global__ __launch_bounds__(256) void k_out(
    const float* __restrict__ x, const unsigned short* __restrict__ T,
    const float* __restrict__ gamma, const float* __restrict__ beta,
    const float* __restrict__ bnS, const float* __restrict__ bnQ,
    float* __restrict__ out)
{
    const int i8 = blockIdx.x * 256 + threadIdx.x;   // 8-elem chunk index
    const int c = (i8 >> 7) & 255;
    const float meanv = bnS[c] * (1.0f / 16384.0f);
    const float varv  = bnQ[c] * (1.0f / 16384.0f) - meanv * meanv;
    const float inv   = rsqrtf(varv + EPS_F);
    const float g = gamma[c] * inv;
    const float be = beta[c];
    const short8 t8 = *(const short8*)(T + (size_t)i8 * 8);
    const unsigned short* tp = (const unsigned short*)&t8;
    const float4 xa = *(const float4*)(x + (size_t)i8 * 8);
    const float4 xb = *(const float4*)(x + (size_t)i8 * 8 + 4);
    float4 oa, ob;
    oa.x = xa.x + fmaxf(g * (b2f(tp[0]) - meanv) + be, 0.0f);
    oa.y = xa.y + fmaxf(g * (b2f(tp[1]) - meanv) + be, 0.0f);
    oa.z = xa.z + fmaxf(g * (b2f(tp[2]) - meanv) + be, 0.0f);
    oa.w = xa.w + fmaxf(g * (b2f(tp[3]) - meanv) + be, 0.0f);
    ob.x = xb.x + fmaxf(g * (b2f(tp[4]) - meanv) + be, 0.0f);
    ob.y = xb.y + fmaxf(g * (b2f(tp[5]) - meanv) + be, 0.0f);
    ob.z = xb.z + fmaxf(g * (b2f(tp[6]) - meanv) + be, 0.0f);
    ob.w = xb.w + fmaxf(g * (b2f(tp[7]) - meanv) + be, 0.0f);
    *(float4*)(out + (size_t)i8 * 8)     = oa;
    *(float4*)(out + (size_t)i8 * 8 + 4) = ob;
}

// ---------------------------------------------------------------------------
extern "C" void kernel_launch(void* const* d_in, const int* in_sizes, int n_in,
                              void* d_out, int out_size, void* d_ws, size_t ws_size,
                              hipStream_t stream)
{
    const float* x     = (const float*)d_in[0];
    const int*   disc  = (const int*)d_in[1];
    // d_in[2] = xyz (unused)
    const float* qw    = (const float*)d_in[3];
    const float* kw    = (const float*)d_in[4];
    const float* vw    = (const float*)d_in[5];
    const float* vb    = (const float*)d_in[6];
    const float* tw    = (const float*)d_in[7];
    const float* tb    = (const float*)d_in[8];
    const float* gamma = (const float*)d_in[9];
    const float* beta  = (const float*)d_in[10];
    const float* xlt   = (const float*)d_in[11];
    const float* ylt   = (const float*)d_in[12];
    const float* zlt   = (const float*)d_in[13];
    float* ws  = (float*)d_ws;
    float* out = (float*)d_out;

    unsigned short* xT  = (unsigned short*)(ws + OFF_XT);
    unsigned short* Qb  = (unsigned short*)(ws + OFF_QB);
    unsigned short* Kbf = (unsigned short*)(ws + OFF_KB);
    float*          QL  = ws + OFF_QL;
    unsigned short* HT  = (unsigned short*)(ws + OFF_HT);
    unsigned short* Vb  = (unsigned short*)(ws + OFF_VB);
    unsigned short* ATT = (unsigned short*)(ws + OFF_ATT);
    unsigned short* T   = (unsigned short*)(ws + OFF_T);
    unsigned short* Wqk = (unsigned short*)(ws + OFF_WQK);
    unsigned short* Wv  = (unsigned short*)(ws + OFF_WV);
    unsigned short* Wt  = (unsigned short*)(ws + OFF_WT);
    float*          bnS = ws + OFF_BNS;
    float*          bnQ = ws + OFF_BNQ;

    hipMemsetAsync(bnS, 0, 512 * sizeof(float), stream);

    k_prep  <<<dim3(160), 256, 0, stream>>>(qw, kw, vw, tw, Wqk, Wv, Wt);
    k_xt    <<<dim3(16, 4, 16), 256, 0, stream>>>(x, xT);
    k_projqk<<<dim3(32, 16), 256, 0, stream>>>(xT, Wqk, Qb, Kbf);
    k_ql    <<<dim3(16, 16), 256, 0, stream>>>(Qb, xlt, ylt, zlt, QL);
    k_projv <<<dim3(32, 16), 256, 0, stream>>>(Wv, xT, vb, Vb);
    k_attn  <<<dim3(64, 16), 256, 0, stream>>>(Qb, Kbf, QL, disc, ATT);
    k_pv    <<<dim3(8, 2, 16), 256, 0, stream>>>(ATT, Vb, xT, HT);
    k_trans <<<dim3(16, 2, 16), 256, 0, stream>>>(Wt, HT, tb, T, bnS, bnQ);
    k_out   <<<dim3(2048), 256, 0, stream>>>(x, T, gamma, beta, bnS, bnQ, out);
}

// Round 7
// 166.008 us; speedup vs baseline: 3.2352x; 1.0459x over previous
//
#include <hip/hip_runtime.h>
#include <math.h>

#define BB 16
#define CC 256
#define NN 1024
#define DQK_ 64
#define DV_ 256
#define NR 192          // 3 * 64 (padded 63-entry tables)
#define EPS_F 1e-5f

// workspace offsets (float units)
#define OFF_XT  ((size_t)0)           // bf16 [B][N][C]   = 2097152 f
#define OFF_QB  ((size_t)2097152)     // bf16 [B][N][64]  = 524288 f
#define OFF_KB  ((size_t)2621440)     // bf16 [B][N][64]  = 524288 f
#define OFF_QL  ((size_t)3145728)     // f32  [B][N][192] = 3145728 f (ends 6291456)
#define OFF_HT  ((size_t)2097152)     // bf16 [B][N][C], overlays QB/KB/QL-head (dead after k_attn)
#define OFF_VB  ((size_t)6291456)     // bf16 [B][DV][N]  = 2097152 f
#define OFF_ATT ((size_t)8388608)     // bf16 [B][N][N]   = 8388608 f (transposed [b][m][n])
#define OFF_T   ((size_t)8388608)     // bf16 [B][C][N], overlays ATT (dead after k_pv)
#define OFF_WQK ((size_t)16777216)    // bf16 [128][256]
#define OFF_WV  ((size_t)16793600)    // bf16 [256][256]
#define OFF_WT  ((size_t)16826368)    // bf16 [256][256]
#define OFF_BNS ((size_t)16859136)
#define OFF_BNQ ((size_t)16859392)
// total 16859648 f = 67.4 MB

typedef __attribute__((ext_vector_type(8))) short short8;
typedef __attribute__((ext_vector_type(4))) float f32x4;

__device__ __forceinline__ unsigned short f2b(float f) {
    unsigned int u = __float_as_uint(f);
    u = u + 0x7fffu + ((u >> 16) & 1u);      // RNE
    return (unsigned short)(u >> 16);
}
__device__ __forceinline__ float b2f(unsigned short s) {
    return __uint_as_float(((unsigned int)s) << 16);
}

// ---------------------------------------------------------------------------
// K0: convert weights to bf16. Wqk = [qw;kw] (128x256), Wv (256x256), Wt (256x256)
__global__ __launch_bounds__(256) void k_prep(
    const float* __restrict__ qw, const float* __restrict__ kw,
    const float* __restrict__ vw, const float* __restrict__ tw,
    unsigned short* __restrict__ Wqk, unsigned short* __restrict__ Wv,
    unsigned short* __restrict__ Wt)
{
    const int o = blockIdx.x * 256 + threadIdx.x;   // quad index, 40960 total
    const float* src; unsigned short* dst;
    if (o < 8192) {
        const int e = o * 4;
        src = (e < 16384) ? (qw + e) : (kw + e - 16384);
        dst = Wqk + e;
    } else if (o < 24576) {
        const int e = (o - 8192) * 4;
        src = vw + e; dst = Wv + e;
    } else {
        const int e = (o - 24576) * 4;
        src = tw + e; dst = Wt + e;
    }
    const float4 v = *(const float4*)src;
    ushort4 u;
    u.x = f2b(v.x); u.y = f2b(v.y); u.z = f2b(v.z); u.w = f2b(v.w);
    *(ushort4*)dst = u;
}

// ---------------------------------------------------------------------------
// K0b: x f32 [b][c][n] -> xT bf16 [b][n][c].  Pad 68 keeps rows 16B-aligned.
__global__ __launch_bounds__(256) void k_xt(
    const float* __restrict__ x, unsigned short* __restrict__ xT)
{
    __shared__ float tile[64][68];
    const int b = blockIdx.z;
    const int c0 = blockIdx.y * 64;
    const int n0 = blockIdx.x * 64;
    const int tid = threadIdx.x;
    #pragma unroll
    for (int it = 0; it < 4; ++it) {
        const int r = it * 16 + (tid >> 4);
        const int c4 = (tid & 15) * 4;
        *(float4*)&tile[r][c4] =
            *(const float4*)(x + ((size_t)b * CC + c0 + r) * NN + n0 + c4);
    }
    __syncthreads();
    const int n = tid >> 2;
    const int cg = (tid & 3) * 16;
    alignas(16) unsigned short buf[16];
    #pragma unroll
    for (int j = 0; j < 16; ++j) buf[j] = f2b(tile[cg + j][n]);
    unsigned short* dst = xT + ((size_t)b * NN + n0 + n) * CC + c0 + cg;
    *(short8*)dst       = *(const short8*)&buf[0];
    *(short8*)(dst + 8) = *(const short8*)&buf[8];
}

// ---------------------------------------------------------------------------
// K1: Q,K projection via MFMA. D[n][ch]: A=xT rows (n), B=Wqk rows (ch).
__global__ __launch_bounds__(256) void k_projqk(
    const unsigned short* __restrict__ xT, const unsigned short* __restrict__ Wqk,
    unsigned short* __restrict__ Qb, unsigned short* __restrict__ Kb)
{
    const int b = blockIdx.y;
    const int n0 = blockIdx.x * 32;
    const int tid = threadIdx.x;
    const int l = tid & 63, w = tid >> 6;
    const int l15 = l & 15, l4 = l >> 4;
    const int ng = (w >> 1) * 16, wh = (w & 1) * 64;
    const unsigned short* ap = xT + ((size_t)b * NN + n0 + ng + l15) * CC + l4 * 8;
    const unsigned short* bp = Wqk + ((size_t)(wh + l15)) * CC + l4 * 8;
    f32x4 z = {0.f, 0.f, 0.f, 0.f};
    f32x4 acc[4] = {z, z, z, z};
    #pragma unroll 2
    for (int kk = 0; kk < CC; kk += 32) {
        const short8 a = *(const short8*)(ap + kk);
        short8 bf[4];
        #pragma unroll
        for (int j = 0; j < 4; ++j)
            bf[j] = *(const short8*)(bp + (size_t)j * 16 * CC + kk);
        #pragma unroll
        for (int j = 0; j < 4; ++j)
            acc[j] = __builtin_amdgcn_mfma_f32_16x16x32_bf16(a, bf[j], acc[j], 0, 0, 0);
    }
    #pragma unroll
    for (int j = 0; j < 4; ++j)
        #pragma unroll
        for (int r = 0; r < 4; ++r) {
            const int n = n0 + ng + l4 * 4 + r;
            const int ch = wh + j * 16 + l15;
            const unsigned short v = f2b(acc[j][r]);
            if (ch < 64) Qb[((size_t)b * NN + n) * DQK_ + ch] = v;
            else         Kb[((size_t)b * NN + n) * DQK_ + ch - 64] = v;
        }
}

// ---------------------------------------------------------------------------
// K1b: QL[b][n][a*64+q] = sum_d Q[n][d] * lt_a[q][d]  (fp32 out, bf16 Q in)
__global__ __launch_bounds__(256) void k_ql(
    const unsigned short* __restrict__ Qb, const float* __restrict__ xlt,
    const float* __restrict__ ylt, const float* __restrict__ zlt,
    float* __restrict__ QL)
{
    __shared__ float QsT[64][68];    // [d][n]
    __shared__ float LTt[64][196];   // [d][a*64+q]
    const int b = blockIdx.y;
    const int n0 = blockIdx.x * 64;
    const int tid = threadIdx.x;
    #pragma unroll
    for (int it = 0; it < 4; ++it) {
        const int i4 = it * 256 + tid;
        const int r  = i4 >> 4;
        const int d4 = (i4 & 15) * 4;
        const ushort4 q4 = *(const ushort4*)(Qb + ((size_t)b * NN + n0 + r) * DQK_ + d4);
        QsT[d4 + 0][r] = b2f(q4.x); QsT[d4 + 1][r] = b2f(q4.y);
        QsT[d4 + 2][r] = b2f(q4.z); QsT[d4 + 3][r] = b2f(q4.w);
    }
    for (int o = tid; o < 12288; o += 256) {
        const int a = o >> 12, rem = o & 4095, q = rem >> 6, d = rem & 63;
        const float* lt = (a == 0) ? xlt : ((a == 1) ? ylt : zlt);
        LTt[d][a * 64 + q] = (q < 63) ? lt[q * 64 + d] : 0.0f;
    }
    __syncthreads();
    const int tn2 = (tid & 15) * 4;
    const int ta  = (tid >> 4) * 12;
    float acc[4][12] = {};
    for (int d = 0; d < 64; ++d) {
        float4 qv = *(float4*)&QsT[d][tn2];
        const float* qp = (const float*)&qv;
        #pragma unroll
        for (int j3 = 0; j3 < 3; ++j3) {
            float4 lv = *(float4*)&LTt[d][ta + j3 * 4];
            const float* lp = (const float*)&lv;
            #pragma unroll
            for (int i = 0; i < 4; ++i)
                #pragma unroll
                for (int jj = 0; jj < 4; ++jj)
                    acc[i][j3 * 4 + jj] += qp[i] * lp[jj];
        }
    }
    #pragma unroll
    for (int i = 0; i < 4; ++i)
        #pragma unroll
        for (int j3 = 0; j3 < 3; ++j3) {
            float4 o4;
            o4.x = acc[i][j3 * 4 + 0]; o4.y = acc[i][j3 * 4 + 1];
            o4.z = acc[i][j3 * 4 + 2]; o4.w = acc[i][j3 * 4 + 3];
            *(float4*)(QL + ((size_t)b * NN + n0 + tn2 + i) * NR + ta + j3 * 4) = o4;
        }
}

// ---------------------------------------------------------------------------
// K2: V projection via MFMA. D[dv][n]: A=Wv rows (dv), B=xT rows (n).
__global__ __launch_bounds__(256) void k_projv(
    const unsigned short* __restrict__ Wv, const unsigned short* __restrict__ xT,
    const float* __restrict__ vb, unsigned short* __restrict__ Vb)
{
    const int b = blockIdx.y;
    const int n0 = blockIdx.x * 32;
    const int tid = threadIdx.x;
    const int l = tid & 63, w = tid >> 6;
    const int l15 = l & 15, l4 = l >> 4;
    const unsigned short* ap = Wv + ((size_t)(w * 64 + l15)) * CC + l4 * 8;
    const unsigned short* bp = xT + ((size_t)b * NN + n0 + l15) * CC + l4 * 8;
    f32x4 z = {0.f, 0.f, 0.f, 0.f};
    f32x4 acc[4][2] = {{z, z}, {z, z}, {z, z}, {z, z}};
    #pragma unroll 2
    for (int kk = 0; kk < CC; kk += 32) {
        short8 af[4], bf[2];
        #pragma unroll
        for (int i = 0; i < 4; ++i)
            af[i] = *(const short8*)(ap + (size_t)i * 16 * CC + kk);
        #pragma unroll
        for (int j = 0; j < 2; ++j)
            bf[j] = *(const short8*)(bp + (size_t)j * 16 * CC + kk);
        #pragma unroll
        for (int i = 0; i < 4; ++i)
            #pragma unroll
            for (int j = 0; j < 2; ++j)
                acc[i][j] = __builtin_amdgcn_mfma_f32_16x16x32_bf16(af[i], bf[j], acc[i][j], 0, 0, 0);
    }
    #pragma unroll
    for (int i = 0; i < 4; ++i)
        #pragma unroll
        for (int r = 0; r < 4; ++r) {
            const int dv = w * 64 + i * 16 + l4 * 4 + r;
            const float bias = vb[dv];
            #pragma unroll
            for (int j = 0; j < 2; ++j) {
                const int n = n0 + j * 16 + l15;
                Vb[((size_t)b * DV_ + dv) * NN + n] = f2b(acc[i][j][r] + bias);
            }
        }
}

// ---------------------------------------------------------------------------
// K3: energy (MFMA, swapped operands) + rel gathers + softmax -> ATT_T bf16.
// 512 threads / 8 waves, 16 q-rows; each q-row spread over 32 lanes -> s[32]
// per lane (frees VGPRs); K fragments double-buffered; dml packed 3->1 int.
__global__ __launch_bounds__(512) void k_attn(
    const unsigned short* __restrict__ Qb, const unsigned short* __restrict__ Kb,
    const float* __restrict__ QL, const int* __restrict__ disc,
    unsigned short* __restrict__ att)
{
    __shared__ float QLs[16][193];
    __shared__ int   dmp[1024];
    __shared__ float redM[8][16];
    __shared__ float redS[8][16];
    const int b = blockIdx.y;
    const int q0 = blockIdx.x * 16;
    const int tid = threadIdx.x;
    const int l = tid & 63, w = tid >> 6;
    const int l15 = l & 15, l4 = l >> 4;

    for (int o = tid; o < 16 * NR; o += 512) {
        const int r = o / NR, c = o - r * NR;
        QLs[r][c] = QL[((size_t)b * NN + q0 + r) * NR + c];
    }
    for (int m = tid; m < NN; m += 512) {
        const size_t base = ((size_t)b * NN + m) * 3;
        dmp[m] = disc[base] | (disc[base + 1] << 8) | (disc[base + 2] << 16);
    }
    __syncthreads();

    const int q = q0 + l15;
    const int dn0 = disc[((size_t)b * NN + q) * 3 + 0] - 31;
    const int dn1 = disc[((size_t)b * NN + q) * 3 + 1] - 31;
    const int dn2 = disc[((size_t)b * NN + q) * 3 + 2] - 31;

    const unsigned short* qp = Qb + ((size_t)b * NN + q) * DQK_ + l4 * 8;
    const short8 qf0 = *(const short8*)qp;
    const short8 qf1 = *(const short8*)(qp + 32);

    const unsigned short* kbase = Kb + (size_t)b * NN * DQK_ + l4 * 8;
    // wave w owns m = t*128 + w*16 + (0..15), t = 0..7
    const unsigned short* kp0 = kbase + (size_t)(w * 16 + l15) * DQK_;
    short8 kf0 = *(const short8*)kp0;
    short8 kf1 = *(const short8*)(kp0 + 32);

    float s[32];
    #pragma unroll
    for (int t = 0; t < 8; ++t) {
        const int tn = (t < 7) ? t + 1 : 7;
        const unsigned short* kpn = kbase + (size_t)(tn * 128 + w * 16 + l15) * DQK_;
        const short8 nf0 = *(const short8*)kpn;
        const short8 nf1 = *(const short8*)(kpn + 32);
        f32x4 acc = {0.f, 0.f, 0.f, 0.f};
        acc = __builtin_amdgcn_mfma_f32_16x16x32_bf16(kf0, qf0, acc, 0, 0, 0);
        acc = __builtin_amdgcn_mfma_f32_16x16x32_bf16(kf1, qf1, acc, 0, 0, 0);
        const int m0 = t * 128 + w * 16 + l4 * 4;
        #pragma unroll
        for (int r = 0; r < 4; ++r) {
            const int pm = dmp[m0 + r];
            const int i0 = (pm & 255) - dn0;
            const int i1 = ((pm >> 8) & 255) - dn1;
            const int i2 = (pm >> 16) - dn2;
            const float rel = QLs[l15][i0] + QLs[l15][64 + i1] + QLs[l15][128 + i2];
            s[t * 4 + r] = (acc[r] + rel) * 0.03125f;
        }
        kf0 = nf0; kf1 = nf1;
    }

    // softmax over m: 32 in-lane, x2 lanes (xor16,32) in-wave, x8 waves via LDS
    float mx = -1e30f;
    #pragma unroll
    for (int i = 0; i < 32; ++i) mx = fmaxf(mx, s[i]);
    mx = fmaxf(mx, __shfl_xor(mx, 16));
    mx = fmaxf(mx, __shfl_xor(mx, 32));
    if (l < 16) redM[w][l] = mx;
    __syncthreads();
    mx = redM[0][l15];
    #pragma unroll
    for (int ww = 1; ww < 8; ++ww) mx = fmaxf(mx, redM[ww][l15]);

    float sum = 0.f;
    #pragma unroll
    for (int i = 0; i < 32; ++i) { s[i] = __expf(s[i] - mx); sum += s[i]; }
    sum += __shfl_xor(sum, 16);
    sum += __shfl_xor(sum, 32);
    if (l < 16) redS[w][l] = sum;
    __syncthreads();
    float tot = redS[0][l15];
    #pragma unroll
    for (int ww = 1; ww < 8; ++ww) tot += redS[ww][l15];
    const float inv = 1.0f / tot;

    #pragma unroll
    for (int t = 0; t < 8; ++t)
        #pragma unroll
        for (int r = 0; r < 4; ++r) {
            const int m = t * 128 + w * 16 + l4 * 4 + r;
            att[((size_t)b * NN + m) * NN + q] = f2b(s[t * 4 + r] * inv);
        }
}

// ---------------------------------------------------------------------------
// K4: XR^T[m][dv] = sum_n ATT_T[m][n] V[dv][n]; fused H^T = x^T - XR^T (bf16).
// Wave tile 64m x 64d (16 MFMA / 8 loads); block 2x2 waves = 128x128;
// explicit 2-buffer register prefetch to hide L2 latency.
__global__ __launch_bounds__(256) void k_pv(
    const unsigned short* __restrict__ att, const unsigned short* __restrict__ Vb,
    const unsigned short* __restrict__ xT, unsigned short* __restrict__ HT)
{
    const int b = blockIdx.z;
    const int d0 = blockIdx.y * 128;
    const int m0 = blockIdx.x * 128;
    const int tid = threadIdx.x;
    const int l = tid & 63, w = tid >> 6;
    const int l15 = l & 15, l4 = l >> 4;
    const int wm = (w & 1) * 64, wd = (w >> 1) * 64;
    const unsigned short* ap = att + ((size_t)b * NN + m0 + wm + l15) * NN + l4 * 8;
    const unsigned short* bp = Vb + ((size_t)b * DV_ + d0 + wd + l15) * NN + l4 * 8;
    f32x4 z = {0.f, 0.f, 0.f, 0.f};
    f32x4 acc[4][4];
    #pragma unroll
    for (int i = 0; i < 4; ++i)
        #pragma unroll
        for (int j = 0; j < 4; ++j) acc[i][j] = z;

    short8 aA[4], bA[4], aB[4], bB[4];
    #pragma unroll
    for (int i = 0; i < 4; ++i) {
        aA[i] = *(const short8*)(ap + (size_t)i * 16 * NN);
        bA[i] = *(const short8*)(bp + (size_t)i * 16 * NN);
    }
    for (int nk = 0; nk < NN; nk += 64) {
        #pragma unroll
        for (int i = 0; i < 4; ++i) {
            aB[i] = *(const short8*)(ap + (size_t)i * 16 * NN + nk + 32);
            bB[i] = *(const short8*)(bp + (size_t)i * 16 * NN + nk + 32);
        }
        #pragma unroll
        for (int i = 0; i < 4; ++i)
            #pragma unroll
            for (int j = 0; j < 4; ++j)
                acc[i][j] = __builtin_amdgcn_mfma_f32_16x16x32_bf16(aA[i], bA[j], acc[i][j], 0, 0, 0);
        if (nk + 64 < NN) {
            #pragma unroll
            for (int i = 0; i < 4; ++i) {
                aA[i] = *(const short8*)(ap + (size_t)i * 16 * NN + nk + 64);
                bA[i] = *(const short8*)(bp + (size_t)i * 16 * NN + nk + 64);
            }
        }
        #pragma unroll
        for (int i = 0; i < 4; ++i)
            #pragma unroll
            for (int j = 0; j < 4; ++j)
                acc[i][j] = __builtin_amdgcn_mfma_f32_16x16x32_bf16(aB[i], bB[j], acc[i][j], 0, 0, 0);
    }
    #pragma unroll
    for (int i = 0; i < 4; ++i)
        #pragma unroll
        for (int r = 0; r < 4; ++r) {
            const int m = m0 + wm + i * 16 + l4 * 4 + r;
            const unsigned short* xrow = xT + ((size_t)b * NN + m) * CC;
            unsigned short* hrow = HT + ((size_t)b * NN + m) * CC;
            #pragma unroll
            for (int j = 0; j < 4; ++j) {
                const int dv = d0 + wd + j * 16 + l15;
                hrow[dv] = f2b(b2f(xrow[dv]) - acc[i][j][r]);
            }
        }
}

// ---------------------------------------------------------------------------
// K5: T[c][n] (bf16) = sum_d Wt[c][d] H^T[n][d] + tb; BN partial sums (f32).
__global__ __launch_bounds__(256) void k_trans(
    const unsigned short* __restrict__ Wt, const unsigned short* __restrict__ HT,
    const float* __restrict__ tb, unsigned short* __restrict__ T,
    float* __restrict__ bnS, float* __restrict__ bnQ)
{
    __shared__ float sS[128], sQ[128];
    const int b = blockIdx.z;
    const int c0 = blockIdx.y * 128;
    const int n0 = blockIdx.x * 64;
    const int tid = threadIdx.x;
    const int l = tid & 63, w = tid >> 6;
    const int l15 = l & 15, l4 = l >> 4;
    const int wc = (w & 1) * 64, wn = (w >> 1) * 32;
    if (tid < 128) { sS[tid] = 0.f; sQ[tid] = 0.f; }
    __syncthreads();
    const unsigned short* ap = Wt + ((size_t)(c0 + wc + l15)) * CC + l4 * 8;
    const unsigned short* bp = HT + ((size_t)b * NN + n0 + wn + l15) * CC + l4 * 8;
    f32x4 z = {0.f, 0.f, 0.f, 0.f};
    f32x4 acc[4][2] = {{z, z}, {z, z}, {z, z}, {z, z}};
    #pragma unroll 2
    for (int kk = 0; kk < CC; kk += 32) {
        short8 af[4], bf[2];
        #pragma unroll
        for (int i = 0; i < 4; ++i)
            af[i] = *(const short8*)(ap + (size_t)i * 16 * CC + kk);
        #pragma unroll
        for (int j = 0; j < 2; ++j)
            bf[j] = *(const short8*)(bp + (size_t)j * 16 * CC + kk);
        #pragma unroll
        for (int i = 0; i < 4; ++i)
            #pragma unroll
            for (int j = 0; j < 2; ++j)
                acc[i][j] = __builtin_amdgcn_mfma_f32_16x16x32_bf16(af[i], bf[j], acc[i][j], 0, 0, 0);
    }
    #pragma unroll
    for (int i = 0; i < 4; ++i)
        #pragma unroll
        for (int r = 0; r < 4; ++r) {
            const int cl = wc + i * 16 + l4 * 4 + r;
            const int c = c0 + cl;
            const float bias = tb[c];
            float s = 0.f, q = 0.f;
            #pragma unroll
            for (int j = 0; j < 2; ++j) {
                const int n = n0 + wn + j * 16 + l15;
                const float t = acc[i][j][r] + bias;
                T[((size_t)b * CC + c) * NN + n] = f2b(t);
                s += t; q += t * t;
            }
            s += __shfl_xor(s, 1); s += __shfl_xor(s, 2);
            s += __shfl_xor(s, 4); s += __shfl_xor(s, 8);
            q += __shfl_xor(q, 1); q += __shfl_xor(q, 2);
            q += __shfl_xor(q, 4); q += __shfl_xor(q, 8);
            if (l15 == 0) {
                atomicAdd(&sS[cl], s);
                atomicAdd(&sQ[cl], q);
            }
        }
    __syncthreads();
    if (tid < 128) {
        atomicAdd(&bnS[c0 + tid], sS[tid]);
        atomicAdd(&bnQ[c0 + tid], sQ[tid]);
    }
}

// ---------------------------------------------------------------------------
// K6: out = x + relu(bn(T)).  8 elems/thread; grid = B*C*N/8/256 = 2048.
__global__ __launch_bounds__(256) void k_out(
    const float* __restrict__ x, const unsigned short* __restrict__ T,
    const float* __restrict__ gamma, const float* __restrict__ beta,
    const float* __restrict__ bnS, const float* __restrict__ bnQ,
    float* __restrict__ out)
{
    const int i8 = blockIdx.x * 256 + threadIdx.x;   // 8-elem chunk index
    const int c = (i8 >> 7) & 255;
    const float meanv = bnS[c] * (1.0f / 16384.0f);
    const float varv  = bnQ[c] * (1.0f / 16384.0f) - meanv * meanv;
    const float inv   = rsqrtf(varv + EPS_F);
    const float g = gamma[c] * inv;
    const float be = beta[c];
    const short8 t8 = *(const short8*)(T + (size_t)i8 * 8);
    const unsigned short* tp = (const unsigned short*)&t8;
    const float4 xa = *(const float4*)(x + (size_t)i8 * 8);
    const float4 xb = *(const float4*)(x + (size_t)i8 * 8 + 4);
    float4 oa, ob;
    oa.x = xa.x + fmaxf(g * (b2f(tp[0]) - meanv) + be, 0.0f);
    oa.y = xa.y + fmaxf(g * (b2f(tp[1]) - meanv) + be, 0.0f);
    oa.z = xa.z + fmaxf(g * (b2f(tp[2]) - meanv) + be, 0.0f);
    oa.w = xa.w + fmaxf(g * (b2f(tp[3]) - meanv) + be, 0.0f);
    ob.x = xb.x + fmaxf(g * (b2f(tp[4]) - meanv) + be, 0.0f);
    ob.y = xb.y + fmaxf(g * (b2f(tp[5]) - meanv) + be, 0.0f);
    ob.z = xb.z + fmaxf(g * (b2f(tp[6]) - meanv) + be, 0.0f);
    ob.w = xb.w + fmaxf(g * (b2f(tp[7]) - meanv) + be, 0.0f);
    *(float4*)(out + (size_t)i8 * 8)     = oa;
    *(float4*)(out + (size_t)i8 * 8 + 4) = ob;
}

// ---------------------------------------------------------------------------
extern "C" void kernel_launch(void* const* d_in, const int* in_sizes, int n_in,
                              void* d_out, int out_size, void* d_ws, size_t ws_size,
                              hipStream_t stream)
{
    const float* x     = (const float*)d_in[0];
    const int*   disc  = (const int*)d_in[1];
    // d_in[2] = xyz (unused)
    const float* qw    = (const float*)d_in[3];
    const float* kw    = (const float*)d_in[4];
    const float* vw    = (const float*)d_in[5];
    const float* vb    = (const float*)d_in[6];
    const float* tw    = (const float*)d_in[7];
    const float* tb    = (const float*)d_in[8];
    const float* gamma = (const float*)d_in[9];
    const float* beta  = (const float*)d_in[10];
    const float* xlt   = (const float*)d_in[11];
    const float* ylt   = (const float*)d_in[12];
    const float* zlt   = (const float*)d_in[13];
    float* ws  = (float*)d_ws;
    float* out = (float*)d_out;

    unsigned short* xT  = (unsigned short*)(ws + OFF_XT);
    unsigned short* Qb  = (unsigned short*)(ws + OFF_QB);
    unsigned short* Kbf = (unsigned short*)(ws + OFF_KB);
    float*          QL  = ws + OFF_QL;
    unsigned short* HT  = (unsigned short*)(ws + OFF_HT);
    unsigned short* Vb  = (unsigned short*)(ws + OFF_VB);
    unsigned short* ATT = (unsigned short*)(ws + OFF_ATT);
    unsigned short* T   = (unsigned short*)(ws + OFF_T);
    unsigned short* Wqk = (unsigned short*)(ws + OFF_WQK);
    unsigned short* Wv  = (unsigned short*)(ws + OFF_WV);
    unsigned short* Wt  = (unsigned short*)(ws + OFF_WT);
    float*          bnS = ws + OFF_BNS;
    float*          bnQ = ws + OFF_BNQ;

    hipMemsetAsync(bnS, 0, 512 * sizeof(float), stream);

    k_prep  <<<dim3(160), 256, 0, stream>>>(qw, kw, vw, tw, Wqk, Wv, Wt);
    k_xt    <<<dim3(16, 4, 16), 256, 0, stream>>>(x, xT);
    k_projqk<<<dim3(32, 16), 256, 0, stream>>>(xT, Wqk, Qb, Kbf);
    k_ql    <<<dim3(16, 16), 256, 0, stream>>>(Qb, xlt, ylt, zlt, QL);
    k_projv <<<dim3(32, 16), 256, 0, stream>>>(Wv, xT, vb, Vb);
    k_attn  <<<dim3(64, 16), 512, 0, stream>>>(Qb, Kbf, QL, disc, ATT);
    k_pv    <<<dim3(8, 2, 16), 256, 0, stream>>>(ATT, Vb, xT, HT);
    k_trans <<<dim3(16, 2, 16), 256, 0, stream>>>(Wt, HT, tb, T, bnS, bnQ);
    k_out   <<<dim3(2048), 256, 0, stream>>>(x, T, gamma, beta, bnS, bnQ, out);
}

// Round 8
// 164.000 us; speedup vs baseline: 3.2748x; 1.0122x over previous
//
#include <hip/hip_runtime.h>
#include <math.h>

#define BB 16
#define CC 256
#define NN 1024
#define DQK_ 64
#define DV_ 256
#define NR 192          // 3 * 64 (padded 63-entry tables)
#define EPS_F 1e-5f

// workspace offsets (float units)
#define OFF_XT  ((size_t)0)           // bf16 [B][N][C]   = 2097152 f
#define OFF_QB  ((size_t)2097152)     // bf16 [B][N][64]  = 524288 f
#define OFF_KB  ((size_t)2621440)     // bf16 [B][N][64]  = 524288 f
#define OFF_QL  ((size_t)3145728)     // f32  [B][N][192] = 3145728 f (ends 6291456)
#define OFF_HT  ((size_t)2097152)     // bf16 [B][N][C], overlays QB/KB/QL-head (dead after k_attn)
#define OFF_VB  ((size_t)6291456)     // bf16 [B][DV][N]  = 2097152 f
#define OFF_ATT ((size_t)8388608)     // bf16 [B][N][N]   = 8388608 f (transposed [b][m][n])
#define OFF_T   ((size_t)8388608)     // bf16 [B][C][N], overlays ATT (dead after k_pv)
#define OFF_WQK ((size_t)16777216)    // bf16 [128][256]
#define OFF_WV  ((size_t)16793600)    // bf16 [256][256]
#define OFF_WT  ((size_t)16826368)    // bf16 [256][256]
#define OFF_BNS ((size_t)16859136)
#define OFF_BNQ ((size_t)16859392)
// total 16859648 f = 67.4 MB

typedef __attribute__((ext_vector_type(8))) short short8;
typedef __attribute__((ext_vector_type(4))) float f32x4;

__device__ __forceinline__ unsigned short f2b(float f) {
    unsigned int u = __float_as_uint(f);
    u = u + 0x7fffu + ((u >> 16) & 1u);      // RNE
    return (unsigned short)(u >> 16);
}
__device__ __forceinline__ float b2f(unsigned short s) {
    return __uint_as_float(((unsigned int)s) << 16);
}

// ---------------------------------------------------------------------------
// K0: convert weights to bf16; block 160 zeroes bnS/bnQ (replaces the 40us
// hipMemsetAsync fillBuffer dispatch).
__global__ __launch_bounds__(256) void k_prep(
    const float* __restrict__ qw, const float* __restrict__ kw,
    const float* __restrict__ vw, const float* __restrict__ tw,
    unsigned short* __restrict__ Wqk, unsigned short* __restrict__ Wv,
    unsigned short* __restrict__ Wt, float* __restrict__ bnS,
    float* __restrict__ bnQ)
{
    if (blockIdx.x == 160) {
        bnS[threadIdx.x] = 0.f;
        bnQ[threadIdx.x] = 0.f;
        return;
    }
    const int o = blockIdx.x * 256 + threadIdx.x;   // quad index, 40960 total
    const float* src; unsigned short* dst;
    if (o < 8192) {
        const int e = o * 4;
        src = (e < 16384) ? (qw + e) : (kw + e - 16384);
        dst = Wqk + e;
    } else if (o < 24576) {
        const int e = (o - 8192) * 4;
        src = vw + e; dst = Wv + e;
    } else {
        const int e = (o - 24576) * 4;
        src = tw + e; dst = Wt + e;
    }
    const float4 v = *(const float4*)src;
    ushort4 u;
    u.x = f2b(v.x); u.y = f2b(v.y); u.z = f2b(v.z); u.w = f2b(v.w);
    *(ushort4*)dst = u;
}

// ---------------------------------------------------------------------------
// K0b: x f32 [b][c][n] -> xT bf16 [b][n][c].  Pad 68 keeps rows 16B-aligned.
__global__ __launch_bounds__(256) void k_xt(
    const float* __restrict__ x, unsigned short* __restrict__ xT)
{
    __shared__ float tile[64][68];
    const int b = blockIdx.z;
    const int c0 = blockIdx.y * 64;
    const int n0 = blockIdx.x * 64;
    const int tid = threadIdx.x;
    #pragma unroll
    for (int it = 0; it < 4; ++it) {
        const int r = it * 16 + (tid >> 4);
        const int c4 = (tid & 15) * 4;
        *(float4*)&tile[r][c4] =
            *(const float4*)(x + ((size_t)b * CC + c0 + r) * NN + n0 + c4);
    }
    __syncthreads();
    const int n = tid >> 2;
    const int cg = (tid & 3) * 16;
    alignas(16) unsigned short buf[16];
    #pragma unroll
    for (int j = 0; j < 16; ++j) buf[j] = f2b(tile[cg + j][n]);
    unsigned short* dst = xT + ((size_t)b * NN + n0 + n) * CC + c0 + cg;
    *(short8*)dst       = *(const short8*)&buf[0];
    *(short8*)(dst + 8) = *(const short8*)&buf[8];
}

// ---------------------------------------------------------------------------
// K1: Q,K projection via MFMA. D[n][ch]: A=xT rows (n), B=Wqk rows (ch).
__global__ __launch_bounds__(256) void k_projqk(
    const unsigned short* __restrict__ xT, const unsigned short* __restrict__ Wqk,
    unsigned short* __restrict__ Qb, unsigned short* __restrict__ Kb)
{
    const int b = blockIdx.y;
    const int n0 = blockIdx.x * 32;
    const int tid = threadIdx.x;
    const int l = tid & 63, w = tid >> 6;
    const int l15 = l & 15, l4 = l >> 4;
    const int ng = (w >> 1) * 16, wh = (w & 1) * 64;
    const unsigned short* ap = xT + ((size_t)b * NN + n0 + ng + l15) * CC + l4 * 8;
    const unsigned short* bp = Wqk + ((size_t)(wh + l15)) * CC + l4 * 8;
    f32x4 z = {0.f, 0.f, 0.f, 0.f};
    f32x4 acc[4] = {z, z, z, z};
    #pragma unroll 2
    for (int kk = 0; kk < CC; kk += 32) {
        const short8 a = *(const short8*)(ap + kk);
        short8 bf[4];
        #pragma unroll
        for (int j = 0; j < 4; ++j)
            bf[j] = *(const short8*)(bp + (size_t)j * 16 * CC + kk);
        #pragma unroll
        for (int j = 0; j < 4; ++j)
            acc[j] = __builtin_amdgcn_mfma_f32_16x16x32_bf16(a, bf[j], acc[j], 0, 0, 0);
    }
    #pragma unroll
    for (int j = 0; j < 4; ++j)
        #pragma unroll
        for (int r = 0; r < 4; ++r) {
            const int n = n0 + ng + l4 * 4 + r;
            const int ch = wh + j * 16 + l15;
            const unsigned short v = f2b(acc[j][r]);
            if (ch < 64) Qb[((size_t)b * NN + n) * DQK_ + ch] = v;
            else         Kb[((size_t)b * NN + n) * DQK_ + ch - 64] = v;
        }
}

// ---------------------------------------------------------------------------
// K1b: QL[b][n][a*64+q] = sum_d Q[n][d] * lt_a[q][d]  (fp32 out, bf16 Q in)
__global__ __launch_bounds__(256) void k_ql(
    const unsigned short* __restrict__ Qb, const float* __restrict__ xlt,
    const float* __restrict__ ylt, const float* __restrict__ zlt,
    float* __restrict__ QL)
{
    __shared__ float QsT[64][68];    // [d][n]
    __shared__ float LTt[64][196];   // [d][a*64+q]
    const int b = blockIdx.y;
    const int n0 = blockIdx.x * 64;
    const int tid = threadIdx.x;
    #pragma unroll
    for (int it = 0; it < 4; ++it) {
        const int i4 = it * 256 + tid;
        const int r  = i4 >> 4;
        const int d4 = (i4 & 15) * 4;
        const ushort4 q4 = *(const ushort4*)(Qb + ((size_t)b * NN + n0 + r) * DQK_ + d4);
        QsT[d4 + 0][r] = b2f(q4.x); QsT[d4 + 1][r] = b2f(q4.y);
        QsT[d4 + 2][r] = b2f(q4.z); QsT[d4 + 3][r] = b2f(q4.w);
    }
    for (int o = tid; o < 12288; o += 256) {
        const int a = o >> 12, rem = o & 4095, q = rem >> 6, d = rem & 63;
        const float* lt = (a == 0) ? xlt : ((a == 1) ? ylt : zlt);
        LTt[d][a * 64 + q] = (q < 63) ? lt[q * 64 + d] : 0.0f;
    }
    __syncthreads();
    const int tn2 = (tid & 15) * 4;
    const int ta  = (tid >> 4) * 12;
    float acc[4][12] = {};
    for (int d = 0; d < 64; ++d) {
        float4 qv = *(float4*)&QsT[d][tn2];
        const float* qp = (const float*)&qv;
        #pragma unroll
        for (int j3 = 0; j3 < 3; ++j3) {
            float4 lv = *(float4*)&LTt[d][ta + j3 * 4];
            const float* lp = (const float*)&lv;
            #pragma unroll
            for (int i = 0; i < 4; ++i)
                #pragma unroll
                for (int jj = 0; jj < 4; ++jj)
                    acc[i][j3 * 4 + jj] += qp[i] * lp[jj];
        }
    }
    #pragma unroll
    for (int i = 0; i < 4; ++i)
        #pragma unroll
        for (int j3 = 0; j3 < 3; ++j3) {
            float4 o4;
            o4.x = acc[i][j3 * 4 + 0]; o4.y = acc[i][j3 * 4 + 1];
            o4.z = acc[i][j3 * 4 + 2]; o4.w = acc[i][j3 * 4 + 3];
            *(float4*)(QL + ((size_t)b * NN + n0 + tn2 + i) * NR + ta + j3 * 4) = o4;
        }
}

// ---------------------------------------------------------------------------
// K2: V projection via MFMA. D[dv][n]: A=Wv rows (dv), B=xT rows (n).
__global__ __launch_bounds__(256) void k_projv(
    const unsigned short* __restrict__ Wv, const unsigned short* __restrict__ xT,
    const float* __restrict__ vb, unsigned short* __restrict__ Vb)
{
    const int b = blockIdx.y;
    const int n0 = blockIdx.x * 32;
    const int tid = threadIdx.x;
    const int l = tid & 63, w = tid >> 6;
    const int l15 = l & 15, l4 = l >> 4;
    const unsigned short* ap = Wv + ((size_t)(w * 64 + l15)) * CC + l4 * 8;
    const unsigned short* bp = xT + ((size_t)b * NN + n0 + l15) * CC + l4 * 8;
    f32x4 z = {0.f, 0.f, 0.f, 0.f};
    f32x4 acc[4][2] = {{z, z}, {z, z}, {z, z}, {z, z}};
    #pragma unroll 2
    for (int kk = 0; kk < CC; kk += 32) {
        short8 af[4], bf[2];
        #pragma unroll
        for (int i = 0; i < 4; ++i)
            af[i] = *(const short8*)(ap + (size_t)i * 16 * CC + kk);
        #pragma unroll
        for (int j = 0; j < 2; ++j)
            bf[j] = *(const short8*)(bp + (size_t)j * 16 * CC + kk);
        #pragma unroll
        for (int i = 0; i < 4; ++i)
            #pragma unroll
            for (int j = 0; j < 2; ++j)
                acc[i][j] = __builtin_amdgcn_mfma_f32_16x16x32_bf16(af[i], bf[j], acc[i][j], 0, 0, 0);
    }
    #pragma unroll
    for (int i = 0; i < 4; ++i)
        #pragma unroll
        for (int r = 0; r < 4; ++r) {
            const int dv = w * 64 + i * 16 + l4 * 4 + r;
            const float bias = vb[dv];
            #pragma unroll
            for (int j = 0; j < 2; ++j) {
                const int n = n0 + j * 16 + l15;
                Vb[((size_t)b * DV_ + dv) * NN + n] = f2b(acc[i][j][r] + bias);
            }
        }
}

// ---------------------------------------------------------------------------
// K3: energy (MFMA, swapped operands) + rel gathers + softmax -> ATT_T bf16.
// 512 threads / 8 waves, 16 q-rows; s[32] per lane; K fragments
// double-buffered; dml packed 3->1 int.
__global__ __launch_bounds__(512) void k_attn(
    const unsigned short* __restrict__ Qb, const unsigned short* __restrict__ Kb,
    const float* __restrict__ QL, const int* __restrict__ disc,
    unsigned short* __restrict__ att)
{
    __shared__ float QLs[16][193];
    __shared__ int   dmp[1024];
    __shared__ float redM[8][16];
    __shared__ float redS[8][16];
    const int b = blockIdx.y;
    const int q0 = blockIdx.x * 16;
    const int tid = threadIdx.x;
    const int l = tid & 63, w = tid >> 6;
    const int l15 = l & 15, l4 = l >> 4;

    for (int o = tid; o < 16 * NR; o += 512) {
        const int r = o / NR, c = o - r * NR;
        QLs[r][c] = QL[((size_t)b * NN + q0 + r) * NR + c];
    }
    for (int m = tid; m < NN; m += 512) {
        const size_t base = ((size_t)b * NN + m) * 3;
        dmp[m] = disc[base] | (disc[base + 1] << 8) | (disc[base + 2] << 16);
    }
    __syncthreads();

    const int q = q0 + l15;
    const int dn0 = disc[((size_t)b * NN + q) * 3 + 0] - 31;
    const int dn1 = disc[((size_t)b * NN + q) * 3 + 1] - 31;
    const int dn2 = disc[((size_t)b * NN + q) * 3 + 2] - 31;

    const unsigned short* qp = Qb + ((size_t)b * NN + q) * DQK_ + l4 * 8;
    const short8 qf0 = *(const short8*)qp;
    const short8 qf1 = *(const short8*)(qp + 32);

    const unsigned short* kbase = Kb + (size_t)b * NN * DQK_ + l4 * 8;
    const unsigned short* kp0 = kbase + (size_t)(w * 16 + l15) * DQK_;
    short8 kf0 = *(const short8*)kp0;
    short8 kf1 = *(const short8*)(kp0 + 32);

    float s[32];
    #pragma unroll
    for (int t = 0; t < 8; ++t) {
        const int tn = (t < 7) ? t + 1 : 7;
        const unsigned short* kpn = kbase + (size_t)(tn * 128 + w * 16 + l15) * DQK_;
        const short8 nf0 = *(const short8*)kpn;
        const short8 nf1 = *(const short8*)(kpn + 32);
        f32x4 acc = {0.f, 0.f, 0.f, 0.f};
        acc = __builtin_amdgcn_mfma_f32_16x16x32_bf16(kf0, qf0, acc, 0, 0, 0);
        acc = __builtin_amdgcn_mfma_f32_16x16x32_bf16(kf1, qf1, acc, 0, 0, 0);
        const int m0 = t * 128 + w * 16 + l4 * 4;
        #pragma unroll
        for (int r = 0; r < 4; ++r) {
            const int pm = dmp[m0 + r];
            const int i0 = (pm & 255) - dn0;
            const int i1 = ((pm >> 8) & 255) - dn1;
            const int i2 = (pm >> 16) - dn2;
            const float rel = QLs[l15][i0] + QLs[l15][64 + i1] + QLs[l15][128 + i2];
            s[t * 4 + r] = (acc[r] + rel) * 0.03125f;
        }
        kf0 = nf0; kf1 = nf1;
    }

    float mx = -1e30f;
    #pragma unroll
    for (int i = 0; i < 32; ++i) mx = fmaxf(mx, s[i]);
    mx = fmaxf(mx, __shfl_xor(mx, 16));
    mx = fmaxf(mx, __shfl_xor(mx, 32));
    if (l < 16) redM[w][l] = mx;
    __syncthreads();
    mx = redM[0][l15];
    #pragma unroll
    for (int ww = 1; ww < 8; ++ww) mx = fmaxf(mx, redM[ww][l15]);

    float sum = 0.f;
    #pragma unroll
    for (int i = 0; i < 32; ++i) { s[i] = __expf(s[i] - mx); sum += s[i]; }
    sum += __shfl_xor(sum, 16);
    sum += __shfl_xor(sum, 32);
    if (l < 16) redS[w][l] = sum;
    __syncthreads();
    float tot = redS[0][l15];
    #pragma unroll
    for (int ww = 1; ww < 8; ++ww) tot += redS[ww][l15];
    const float inv = 1.0f / tot;

    #pragma unroll
    for (int t = 0; t < 8; ++t)
        #pragma unroll
        for (int r = 0; r < 4; ++r) {
            const int m = t * 128 + w * 16 + l4 * 4 + r;
            att[((size_t)b * NN + m) * NN + q] = f2b(s[t * 4 + r] * inv);
        }
}

// ---------------------------------------------------------------------------
// K4: XR^T[m][dv] = sum_n ATT_T[m][n] V[dv][n]; fused H^T = x^T - XR^T (bf16).
// Wave tile 64m x 64d (16 MFMA / 8 loads); block 2x2 waves = 128x128;
// explicit 2-buffer register prefetch to hide L2 latency.
__global__ __launch_bounds__(256) void k_pv(
    const unsigned short* __restrict__ att, const unsigned short* __restrict__ Vb,
    const unsigned short* __restrict__ xT, unsigned short* __restrict__ HT)
{
    const int b = blockIdx.z;
    const int d0 = blockIdx.y * 128;
    const int m0 = blockIdx.x * 128;
    const int tid = threadIdx.x;
    const int l = tid & 63, w = tid >> 6;
    const int l15 = l & 15, l4 = l >> 4;
    const int wm = (w & 1) * 64, wd = (w >> 1) * 64;
    const unsigned short* ap = att + ((size_t)b * NN + m0 + wm + l15) * NN + l4 * 8;
    const unsigned short* bp = Vb + ((size_t)b * DV_ + d0 + wd + l15) * NN + l4 * 8;
    f32x4 z = {0.f, 0.f, 0.f, 0.f};
    f32x4 acc[4][4];
    #pragma unroll
    for (int i = 0; i < 4; ++i)
        #pragma unroll
        for (int j = 0; j < 4; ++j) acc[i][j] = z;

    short8 aA[4], bA[4], aB[4], bB[4];
    #pragma unroll
    for (int i = 0; i < 4; ++i) {
        aA[i] = *(const short8*)(ap + (size_t)i * 16 * NN);
        bA[i] = *(const short8*)(bp + (size_t)i * 16 * NN);
    }
    for (int nk = 0; nk < NN; nk += 64) {
        #pragma unroll
        for (int i = 0; i < 4; ++i) {
            aB[i] = *(const short8*)(ap + (size_t)i * 16 * NN + nk + 32);
            bB[i] = *(const short8*)(bp + (size_t)i * 16 * NN + nk + 32);
        }
        #pragma unroll
        for (int i = 0; i < 4; ++i)
            #pragma unroll
            for (int j = 0; j < 4; ++j)
                acc[i][j] = __builtin_amdgcn_mfma_f32_16x16x32_bf16(aA[i], bA[j], acc[i][j], 0, 0, 0);
        if (nk + 64 < NN) {
            #pragma unroll
            for (int i = 0; i < 4; ++i) {
                aA[i] = *(const short8*)(ap + (size_t)i * 16 * NN + nk + 64);
                bA[i] = *(const short8*)(bp + (size_t)i * 16 * NN + nk + 64);
            }
        }
        #pragma unroll
        for (int i = 0; i < 4; ++i)
            #pragma unroll
            for (int j = 0; j < 4; ++j)
                acc[i][j] = __builtin_amdgcn_mfma_f32_16x16x32_bf16(aB[i], bB[j], acc[i][j], 0, 0, 0);
    }
    #pragma unroll
    for (int i = 0; i < 4; ++i)
        #pragma unroll
        for (int r = 0; r < 4; ++r) {
            const int m = m0 + wm + i * 16 + l4 * 4 + r;
            const unsigned short* xrow = xT + ((size_t)b * NN + m) * CC;
            unsigned short* hrow = HT + ((size_t)b * NN + m) * CC;
            #pragma unroll
            for (int j = 0; j < 4; ++j) {
                const int dv = d0 + wd + j * 16 + l15;
                hrow[dv] = f2b(b2f(xrow[dv]) - acc[i][j][r]);
            }
        }
}

// ---------------------------------------------------------------------------
// K5: T[c][n] (bf16) = sum_d Wt[c][d] H^T[n][d] + tb; BN partial sums (f32).
__global__ __launch_bounds__(256) void k_trans(
    const unsigned short* __restrict__ Wt, const unsigned short* __restrict__ HT,
    const float* __restrict__ tb, unsigned short* __restrict__ T,
    float* __restrict__ bnS, float* __restrict__ bnQ)
{
    __shared__ float sS[128], sQ[128];
    const int b = blockIdx.z;
    const int c0 = blockIdx.y * 128;
    const int n0 = blockIdx.x * 64;
    const int tid = threadIdx.x;
    const int l = tid & 63, w = tid >> 6;
    const int l15 = l & 15, l4 = l >> 4;
    const int wc = (w & 1) * 64, wn = (w >> 1) * 32;
    if (tid < 128) { sS[tid] = 0.f; sQ[tid] = 0.f; }
    __syncthreads();
    const unsigned short* ap = Wt + ((size_t)(c0 + wc + l15)) * CC + l4 * 8;
    const unsigned short* bp = HT + ((size_t)b * NN + n0 + wn + l15) * CC + l4 * 8;
    f32x4 z = {0.f, 0.f, 0.f, 0.f};
    f32x4 acc[4][2] = {{z, z}, {z, z}, {z, z}, {z, z}};
    #pragma unroll 2
    for (int kk = 0; kk < CC; kk += 32) {
        short8 af[4], bf[2];
        #pragma unroll
        for (int i = 0; i < 4; ++i)
            af[i] = *(const short8*)(ap + (size_t)i * 16 * CC + kk);
        #pragma unroll
        for (int j = 0; j < 2; ++j)
            bf[j] = *(const short8*)(bp + (size_t)j * 16 * CC + kk);
        #pragma unroll
        for (int i = 0; i < 4; ++i)
            #pragma unroll
            for (int j = 0; j < 2; ++j)
                acc[i][j] = __builtin_amdgcn_mfma_f32_16x16x32_bf16(af[i], bf[j], acc[i][j], 0, 0, 0);
    }
    #pragma unroll
    for (int i = 0; i < 4; ++i)
        #pragma unroll
        for (int r = 0; r < 4; ++r) {
            const int cl = wc + i * 16 + l4 * 4 + r;
            const int c = c0 + cl;
            const float bias = tb[c];
            float s = 0.f, q = 0.f;
            #pragma unroll
            for (int j = 0; j < 2; ++j) {
                const int n = n0 + wn + j * 16 + l15;
                const float t = acc[i][j][r] + bias;
                T[((size_t)b * CC + c) * NN + n] = f2b(t);
                s += t; q += t * t;
            }
            s += __shfl_xor(s, 1); s += __shfl_xor(s, 2);
            s += __shfl_xor(s, 4); s += __shfl_xor(s, 8);
            q += __shfl_xor(q, 1); q += __shfl_xor(q, 2);
            q += __shfl_xor(q, 4); q += __shfl_xor(q, 8);
            if (l15 == 0) {
                atomicAdd(&sS[cl], s);
                atomicAdd(&sQ[cl], q);
            }
        }
    __syncthreads();
    if (tid < 128) {
        atomicAdd(&bnS[c0 + tid], sS[tid]);
        atomicAdd(&bnQ[c0 + tid], sQ[tid]);
    }
}

// ---------------------------------------------------------------------------
// K6: out = x + relu(bn(T)).  8 elems/thread; grid = B*C*N/8/256 = 2048.
__global__ __launch_bounds__(256) void k_out(
    const float* __restrict__ x, const unsigned short* __restrict__ T,
    const float* __restrict__ gamma, const float* __restrict__ beta,
    const float* __restrict__ bnS, const float* __restrict__ bnQ,
    float* __restrict__ out)
{
    const int i8 = blockIdx.x * 256 + threadIdx.x;   // 8-elem chunk index
    const int c = (i8 >> 7) & 255;
    const float meanv = bnS[c] * (1.0f / 16384.0f);
    const float varv  = bnQ[c] * (1.0f / 16384.0f) - meanv * meanv;
    const float inv   = rsqrtf(varv + EPS_F);
    const float g = gamma[c] * inv;
    const float be = beta[c];
    const short8 t8 = *(const short8*)(T + (size_t)i8 * 8);
    const unsigned short* tp = (const unsigned short*)&t8;
    const float4 xa = *(const float4*)(x + (size_t)i8 * 8);
    const float4 xb = *(const float4*)(x + (size_t)i8 * 8 + 4);
    float4 oa, ob;
    oa.x = xa.x + fmaxf(g * (b2f(tp[0]) - meanv) + be, 0.0f);
    oa.y = xa.y + fmaxf(g * (b2f(tp[1]) - meanv) + be, 0.0f);
    oa.z = xa.z + fmaxf(g * (b2f(tp[2]) - meanv) + be, 0.0f);
    oa.w = xa.w + fmaxf(g * (b2f(tp[3]) - meanv) + be, 0.0f);
    ob.x = xb.x + fmaxf(g * (b2f(tp[4]) - meanv) + be, 0.0f);
    ob.y = xb.y + fmaxf(g * (b2f(tp[5]) - meanv) + be, 0.0f);
    ob.z = xb.z + fmaxf(g * (b2f(tp[6]) - meanv) + be, 0.0f);
    ob.w = xb.w + fmaxf(g * (b2f(tp[7]) - meanv) + be, 0.0f);
    *(float4*)(out + (size_t)i8 * 8)     = oa;
    *(float4*)(out + (size_t)i8 * 8 + 4) = ob;
}

// ---------------------------------------------------------------------------
extern "C" void kernel_launch(void* const* d_in, const int* in_sizes, int n_in,
                              void* d_out, int out_size, void* d_ws, size_t ws_size,
                              hipStream_t stream)
{
    const float* x     = (const float*)d_in[0];
    const int*   disc  = (const int*)d_in[1];
    // d_in[2] = xyz (unused)
    const float* qw    = (const float*)d_in[3];
    const float* kw    = (const float*)d_in[4];
    const float* vw    = (const float*)d_in[5];
    const float* vb    = (const float*)d_in[6];
    const float* tw    = (const float*)d_in[7];
    const float* tb    = (const float*)d_in[8];
    const float* gamma = (const float*)d_in[9];
    const float* beta  = (const float*)d_in[10];
    const float* xlt   = (const float*)d_in[11];
    const float* ylt   = (const float*)d_in[12];
    const float* zlt   = (const float*)d_in[13];
    float* ws  = (float*)d_ws;
    float* out = (float*)d_out;

    unsigned short* xT  = (unsigned short*)(ws + OFF_XT);
    unsigned short* Qb  = (unsigned short*)(ws + OFF_QB);
    unsigned short* Kbf = (unsigned short*)(ws + OFF_KB);
    float*          QL  = ws + OFF_QL;
    unsigned short* HT  = (unsigned short*)(ws + OFF_HT);
    unsigned short* Vb  = (unsigned short*)(ws + OFF_VB);
    unsigned short* ATT = (unsigned short*)(ws + OFF_ATT);
    unsigned short* T   = (unsigned short*)(ws + OFF_T);
    unsigned short* Wqk = (unsigned short*)(ws + OFF_WQK);
    unsigned short* Wv  = (unsigned short*)(ws + OFF_WV);
    unsigned short* Wt  = (unsigned short*)(ws + OFF_WT);
    float*          bnS = ws + OFF_BNS;
    float*          bnQ = ws + OFF_BNQ;

    k_prep  <<<dim3(161), 256, 0, stream>>>(qw, kw, vw, tw, Wqk, Wv, Wt, bnS, bnQ);
    k_xt    <<<dim3(16, 4, 16), 256, 0, stream>>>(x, xT);
    k_projqk<<<dim3(32, 16), 256, 0, stream>>>(xT, Wqk, Qb, Kbf);
    k_ql    <<<dim3(16, 16), 256, 0, stream>>>(Qb, xlt, ylt, zlt, QL);
    k_projv <<<dim3(32, 16), 256, 0, stream>>>(Wv, xT, vb, Vb);
    k_attn  <<<dim3(64, 16), 512, 0, stream>>>(Qb, Kbf, QL, disc, ATT);
    k_pv    <<<dim3(8, 2, 16), 256, 0, stream>>>(ATT, Vb, xT, HT);
    k_trans <<<dim3(16, 2, 16), 256, 0, stream>>>(Wt, HT, tb, T, bnS, bnQ);
    k_out   <<<dim3(2048), 256, 0, stream>>>(x, T, gamma, beta, bnS, bnQ, out);
}